// Round 13
// baseline (290.975 us; speedup 1.0000x reference)
//
#include <hip/hip_runtime.h>
#include <hip/hip_bf16.h>
#include <cstdint>
#include <cstddef>

#define BQ 128        // queries (problem-fixed)
#define DK 192        // SIG_DIM
#define KTOP 32
#define CHI 32        // gallery items per chunk
#define SLOTS 2       // candidate slots per (query, chunk)
#define QCAP 512      // per-chunk LDS rescore queue
#define OCAP 65536    // global overflow list
#define MARGIN 0.02f  // > 2x (trunc-G + rne-Q) dot error bound (~0.012)
#define THRV 3200     // thr32 LDS value slots
#define GRIDP 256     // persistent blocks: 1/CU (LDS-bound)
#define NSAMP 3       // samples per block in mode 0 -> SC = 768
#define CNTL 6400     // select: LDS-cached per-chunk counts

#define NEG_INF (-__builtin_huge_valf())

typedef short short8v __attribute__((ext_vector_type(8)));
typedef float f32x16  __attribute__((ext_vector_type(16)));

__device__ __forceinline__ unsigned fkey(float s) {
    unsigned u = __float_as_uint(s);
    return (u & 0x80000000u) ? ~u : (u | 0x80000000u);   // monotone f32 -> u32
}
__device__ __forceinline__ bool pri_gt(float s1, int i1, float s2, int i2) {
    return (s1 > s2) || (s1 == s2 && i1 < i2);           // jax top_k stability
}
// pack {bf16_trunc(b) : bf16_trunc(a)} in one v_perm_b32 (high halves)
__device__ __forceinline__ unsigned pk_trunc(float a, float b) {
    return __builtin_amdgcn_perm(__float_as_uint(b), __float_as_uint(a),
                                 0x07060302u);
}
__device__ __forceinline__ unsigned f2bf_rne(float x) {
    unsigned u = __float_as_uint(x);
    unsigned r = u + 0x7FFFu + ((u >> 16) & 1u);
    return r >> 16;
}
__device__ __forceinline__ float dot192(const float* __restrict__ a,
                                        const float* __restrict__ b) {
    float s = 0.f;
    #pragma unroll 8
    for (int k = 0; k < DK; ++k) s = fmaf(a[k], b[k], s);
    return s;
}
// async global->LDS DMA, 16B per lane; LDS base wave-uniform (HW adds lane*16)
__device__ __forceinline__ void gload_lds16(const void* g, void* l) {
    __builtin_amdgcn_global_load_lds(
        (const __attribute__((address_space(1))) unsigned int*)g,
        (__attribute__((address_space(3))) unsigned int*)l,
        16, 0, 0);
}

// ---------------------------------------------------------------------------
// MFMA scoring pass, 32-item chunks x all 128 queries. ZERO long-lived VGPR
// state (the r10/11/12 spill killer): Q lives in LDS as bf16 (staged once
// per block, XOR-swizzled), G staged fp32 via global_load_lds DMA
// (double-buffered, pre-swizzled source), fragments ds_read per step.
// MODE 0: NSAMP strided sample chunks/block: masked bf16 max -> gmax[it][q]
// MODE 1: persistent filter: one-ahead DMA pipeline, threshold filter ->
//         LDS queue -> exact fp32 rescore -> slotted store
// ---------------------------------------------------------------------------
template<int MODE>
__global__ __launch_bounds__(256) void score_pass(
    const float* __restrict__ Qf, const float* __restrict__ G,
    const int* __restrict__ mask, const float* __restrict__ thrm,
    float* __restrict__ gmax,
    int* __restrict__ cnt2, float* __restrict__ cs, int* __restrict__ ci,
    int* __restrict__ ocnt, int* __restrict__ oq, int* __restrict__ og,
    float* __restrict__ osv,
    int Ntot, int NCH, int SC)
{
    __shared__ unsigned char Qlds[BQ * 384];   // 48 KB bf16 Q, swizzled blocks
    __shared__ float    Gf[2][CHI * DK];       // 48 KB fp32 G double buffer
    __shared__ float    thrmS[BQ];
    __shared__ unsigned queue[QCAP];
    __shared__ int      lcnt[BQ];
    __shared__ int      qn;

    const int t = threadIdx.x;
    const int w = t >> 6, lane = t & 63;
    const int lo5 = lane & 31, hi = lane >> 5;
    const int qbW = w * 32;

    if (t < BQ) { thrmS[t] = (MODE == 1) ? thrm[t] : 0.f; lcnt[t] = 0; }
    if (t == 0) qn = 0;

    // ---- stage Q -> LDS bf16 (RNE), XOR-swizzled 16B blocks, once per block
    {
        #pragma unroll
        for (int i = 0; i < 12; ++i) {
            const int blk = t + (i << 8);          // 0..3071
            const int row = blk / 24, c = blk - row * 24;
            const float* qp = Qf + row * DK + c * 8;
            float4 x = *reinterpret_cast<const float4*>(qp);
            float4 y = *reinterpret_cast<const float4*>(qp + 4);
            uint4 p;
            p.x = f2bf_rne(x.x) | (f2bf_rne(x.y) << 16);
            p.y = f2bf_rne(x.z) | (f2bf_rne(x.w) << 16);
            p.z = f2bf_rne(y.x) | (f2bf_rne(y.y) << 16);
            p.w = f2bf_rne(y.z) | (f2bf_rne(y.w) << 16);
            *reinterpret_cast<uint4*>(
                Qlds + row * 384 + ((c ^ (row & 7)) << 4)) = p;
        }
    }

    // per-lane DMA staging geometry: slot covers 32 rows x 48 16B-blocks
    int srow[6], swz[6];
    #pragma unroll
    for (int i = 0; i < 6; ++i) {
        const int slot = t + (i << 8);
        const int r = slot / 48, c = slot - r * 48;
        srow[i] = r;
        swz[i]  = ((c ^ (r & 7)) << 4);            // pre-swizzled global block
    }

    auto STAGE = [&](int chunk, int buf) {
        const size_t cb = (size_t)chunk * CHI;
        #pragma unroll
        for (int i = 0; i < 6; ++i) {
            size_t grow = cb + srow[i];
            if (grow >= (size_t)Ntot) grow = (size_t)Ntot - 1;  // safe dup
            const char* gp = (const char*)G + grow * (DK * 4) + swz[i];
            char* lp = (char*)&Gf[buf][0] + ((i << 2) + w) * 1024; // wave-uniform
            gload_lds16(gp, lp);
        }
    };

    const int step = (int)gridDim.x;
    int it = blockIdx.x;
    const int itEnd = (MODE == 0) ? SC : NCH;
    auto CHUNK_OF = [&](int idx) {
        return (MODE == 0) ? (int)(((long long)idx * NCH) / SC) : idx;
    };

    if (it < itEnd) STAGE(CHUNK_OF(it), 0);
    __syncthreads();                    // drains DMA + Q staging visible
    int pb = 0;

    const unsigned xsh = (unsigned)((lo5 & 7) << 4);
    const unsigned abase = (unsigned)((qbW + lo5) * 384);
    const unsigned browoff = (unsigned)(lo5 * (DK * 4));

    while (it < itEnd) {
        const int ch = CHUNK_OF(it);
        const int cb = ch * CHI;
        const int itn = it + step;
        const bool more = itn < itEnd;
        if (more) STAGE(CHUNK_OF(itn), pb ^ 1);    // async under this compute

        const char* rowp = (const char*)&Gf[pb][0] + browoff;
        f32x16 acc = {0,0,0,0,0,0,0,0,0,0,0,0,0,0,0,0};
        #pragma unroll
        for (int s = 0; s < 12; ++s) {
            union { uint4 u; short8v v; } au;
            au.u = *reinterpret_cast<const uint4*>(
                Qlds + abase + ((unsigned)(((s << 1) + hi) << 4) ^ xsh));
            const unsigned b0 = ((unsigned)((s * 4 + hi * 2) << 4)) ^ xsh;
            const unsigned b1 = ((unsigned)((s * 4 + hi * 2 + 1) << 4)) ^ xsh;
            float4 f0 = *reinterpret_cast<const float4*>(rowp + b0);
            float4 f1 = *reinterpret_cast<const float4*>(rowp + b1);
            union { unsigned u[4]; short8v v; } bu;
            bu.u[0] = pk_trunc(f0.x, f0.y); bu.u[1] = pk_trunc(f0.z, f0.w);
            bu.u[2] = pk_trunc(f1.x, f1.y); bu.u[3] = pk_trunc(f1.z, f1.w);
            acc = __builtin_amdgcn_mfma_f32_32x32x16_bf16(au.v, bu.v, acc, 0, 0, 0);
        }

        // C layout (32x32): col(item)=lane&31, row(query)=(j&3)+8*(j>>2)+4*hi
        if (MODE == 0) {
            #pragma unroll
            for (int j = 0; j < 16; ++j) {
                const int row = (j & 3) + 8 * (j >> 2) + 4 * hi;
                const int q = qbW + row;
                const int g = cb + lo5;
                float m = NEG_INF;
                if (g < Ntot && !mask[(size_t)q * (size_t)Ntot + g])
                    m = acc[j];
                #pragma unroll
                for (int off = 1; off < 32; off <<= 1)
                    m = fmaxf(m, __shfl_xor(m, off));
                if (lo5 == 0) gmax[(size_t)it * BQ + q] = m;   // sample index
            }
        } else {
            #pragma unroll
            for (int j = 0; j < 16; ++j) {
                const int row = (j & 3) + 8 * (j >> 2) + 4 * hi;
                const int q = qbW + row;
                const float th = thrmS[q];
                const int g = cb + lo5;
                const float s = acc[j];
                if (g < Ntot && s >= th) {
                    if (!mask[(size_t)q * (size_t)Ntot + g]) {
                        const int p = atomicAdd(&qn, 1);
                        if (p < QCAP) {
                            queue[p] = ((unsigned)q << 24) | (unsigned)g;
                        } else {   // pathological: inline exact rescore
                            float sx = dot192(Qf + q * DK, G + (size_t)g * DK);
                            const int op = atomicAdd(ocnt, 1);
                            if (op < OCAP) { oq[op] = q; og[op] = g; osv[op] = sx; }
                        }
                    }
                }
            }
            __syncthreads();
            const int nq = qn < QCAP ? qn : QCAP;
            for (int cc = w; cc < nq; cc += 4) {       // one wave per candidate
                const unsigned pk = queue[cc];
                const int q = pk >> 24, g = pk & 0xFFFFFF;
                const float* qr = Qf + q * DK;
                const float* gr = G + (size_t)g * DK;
                const int k0 = lane * 3;
                float part = qr[k0] * gr[k0];
                part = fmaf(qr[k0 + 1], gr[k0 + 1], part);
                part = fmaf(qr[k0 + 2], gr[k0 + 2], part);
                #pragma unroll
                for (int off = 32; off > 0; off >>= 1)
                    part += __shfl_xor(part, off);
                if (lane == 0) {
                    const int p = atomicAdd(&lcnt[q], 1);
                    if (p < SLOTS) {
                        const size_t o = ((size_t)q * NCH + ch) * SLOTS + p;
                        cs[o] = part; ci[o] = g;
                    } else {
                        const int op = atomicAdd(ocnt, 1);
                        if (op < OCAP) { oq[op] = q; og[op] = g; osv[op] = part; }
                    }
                }
            }
            __syncthreads();
            if (t < BQ) {
                int v = lcnt[t]; if (v > SLOTS) v = SLOTS;
                cnt2[(size_t)t * NCH + ch] = v;
                lcnt[t] = 0;
            }
            if (t == 0) qn = 0;
        }

        __syncthreads();   // next tile's DMA drained; LDS reuse safe
        pb ^= 1;
        it = itn;
    }
}

// ---------------------------------------------------------------------------
// thrm[q] = (exact 32nd-largest of SC sampled masked chunk-maxima) - MARGIN.
// Valid bound: 32 distinct unmasked witnesses with bf16 score >= thr.
// ---------------------------------------------------------------------------
__global__ __launch_bounds__(256) void thr32(
    const float* __restrict__ gmax, float* __restrict__ thrm, int SC)
{
    __shared__ float vals[THRV];
    __shared__ int hist[256];
    __shared__ int hscan[256];
    __shared__ int bS, gtS;

    const int q = blockIdx.x;
    const int t = threadIdx.x;
    const int M = SC < THRV ? SC : THRV;

    for (int i = t; i < M; i += 256) {
        float m = gmax[(size_t)i * BQ + q];
        for (int j = i + THRV; j < SC; j += THRV)
            m = fmaxf(m, gmax[(size_t)j * BQ + q]);
        vals[i] = m;
    }
    __syncthreads();

    unsigned prefix = 0, pmask = 0;
    int kneed = KTOP;
    for (int pass = 0; pass < 4; ++pass) {
        const int shift = 24 - pass * 8;
        hist[t] = 0;
        __syncthreads();
        for (int i = t; i < M; i += 256) {
            unsigned k = fkey(vals[i]);
            if ((k & pmask) == prefix) atomicAdd(&hist[(k >> shift) & 255], 1);
        }
        __syncthreads();
        int* src = hist; int* dst = hscan;
        for (int off = 1; off < 256; off <<= 1) {
            int v = src[t] + ((t + off) < 256 ? src[t + off] : 0);
            __syncthreads();
            dst[t] = v;
            __syncthreads();
            int* tmp = src; src = dst; dst = tmp;
        }
        if (src[t] >= kneed && (t == 255 || src[t + 1] < kneed)) {
            bS = t; gtS = (t == 255) ? 0 : src[t + 1];
        }
        __syncthreads();
        kneed -= gtS;
        prefix |= ((unsigned)bS) << shift;
        pmask  |= 0xFFu << shift;
        __syncthreads();
    }
    if (t == 0) {
        unsigned u = (prefix & 0x80000000u) ? (prefix & 0x7FFFFFFFu) : ~prefix;
        thrm[q] = __uint_as_float(u) - MARGIN;
    }
}

// ---------------------------------------------------------------------------
// Exact per-query top-32 over slotted candidates (+overflow): 4-pass radix
// select + collect + tie-breaking tournament (score desc, idx asc).
// out: [0..B*K) = indices (as float); [B*K..2BK) = scores.
// ---------------------------------------------------------------------------
__global__ __launch_bounds__(256) void select_topk(
    const float* __restrict__ cs, const int* __restrict__ ci,
    const int* __restrict__ cnt2,
    const int* __restrict__ ocnt, const int* __restrict__ oq,
    const int* __restrict__ og, const float* __restrict__ osv,
    float* __restrict__ out, int CBLK)
{
    __shared__ int   cntRow[CNTL];
    __shared__ int   hist[256];
    __shared__ int   hscan[256];
    __shared__ float Ls[256];
    __shared__ int   Li[256];
    __shared__ int   lcnt, nTotS, bS, gtS;
    __shared__ float wrs[4]; __shared__ int wri[4], wrslot[4];

    const int q = blockIdx.x;
    const int t = threadIdx.x;
    const size_t qbase = (size_t)q * CBLK * SLOTS;
    const size_t cbase = (size_t)q * CBLK;
    const int CC = CBLK < CNTL ? CBLK : CNTL;
    const int novf0 = *ocnt;
    const int novf = novf0 < OCAP ? novf0 : OCAP;
    const int nslots = CBLK * SLOTS;

    for (int i = t; i < CC; i += 256) cntRow[i] = cnt2[cbase + i];
    if (t == 0) nTotS = 0;
    __syncthreads();
    {
        int part = 0;
        for (int i = t; i < CBLK; i += 256)
            part += (i < CNTL) ? cntRow[i] : cnt2[cbase + i];
        for (int i = t; i < novf; i += 256)
            if (oq[i] == q) part++;
        atomicAdd(&nTotS, part);
    }
    __syncthreads();
    const int nTot = nTotS;

    unsigned prefix = 0, pmask = 0;
    int kneed = KTOP;

    if (nTot > KTOP) {
        for (int pass = 0; pass < 4; ++pass) {
            const int shift = 24 - pass * 8;
            hist[t] = 0;
            __syncthreads();
            for (int i = t; i < nslots; i += 256) {
                const int b = i >> 1, sl = i & 1;          // SLOTS = 2
                const int cb = (b < CNTL) ? cntRow[b] : cnt2[cbase + b];
                if (sl < cb) {
                    unsigned k = fkey(cs[qbase + i]);
                    if ((k & pmask) == prefix)
                        atomicAdd(&hist[(k >> shift) & 255], 1);
                }
            }
            for (int i = t; i < novf; i += 256) {
                if (oq[i] == q) {
                    unsigned k = fkey(osv[i]);
                    if ((k & pmask) == prefix)
                        atomicAdd(&hist[(k >> shift) & 255], 1);
                }
            }
            __syncthreads();
            int* src = hist; int* dst = hscan;
            for (int off = 1; off < 256; off <<= 1) {
                int v = src[t] + ((t + off) < 256 ? src[t + off] : 0);
                __syncthreads();
                dst[t] = v;
                __syncthreads();
                int* tmp = src; src = dst; dst = tmp;
            }
            if (src[t] >= kneed && (t == 255 || src[t + 1] < kneed)) {
                bS = t;
                gtS = (t == 255) ? 0 : src[t + 1];
            }
            __syncthreads();
            const int b = bS;
            kneed -= gtS;
            prefix |= ((unsigned)b) << shift;
            pmask  |= 0xFFu << shift;
            __syncthreads();
        }
    }

    if (t == 0) lcnt = 0;
    __syncthreads();
    const unsigned T = (nTot > KTOP) ? prefix : 0u;
    for (int i = t; i < nslots; i += 256) {
        const int b = i >> 1, sl = i & 1;
        const int cb = (b < CNTL) ? cntRow[b] : cnt2[cbase + b];
        if (sl < cb) {
            float s = cs[qbase + i];
            if (fkey(s) >= T) {
                int p = atomicAdd(&lcnt, 1);
                if (p < 256) { Ls[p] = s; Li[p] = ci[qbase + i]; }
            }
        }
    }
    for (int i = t; i < novf; i += 256) {
        if (oq[i] == q) {
            float s = osv[i];
            if (fkey(s) >= T) {
                int p = atomicAdd(&lcnt, 1);
                if (p < 256) { Ls[p] = s; Li[p] = og[i]; }
            }
        }
    }
    __syncthreads();
    const int M = lcnt < 256 ? lcnt : 256;

    const int w = t >> 6, lane = t & 63;
    for (int r = 0; r < KTOP; ++r) {
        float bv = (t < M) ? Ls[t] : NEG_INF;
        int   bi = (t < M) ? Li[t] : 0x7fffffff;
        int   bslot = t;
        #pragma unroll
        for (int off = 32; off > 0; off >>= 1) {
            float ov = __shfl_xor(bv, off);
            int   oi = __shfl_xor(bi, off);
            int   osl = __shfl_xor(bslot, off);
            if (pri_gt(ov, oi, bv, bi)) { bv = ov; bi = oi; bslot = osl; }
        }
        if (lane == 0) { wrs[w] = bv; wri[w] = bi; wrslot[w] = bslot; }
        __syncthreads();
        if (t == 0) {
            float fv = wrs[0]; int fi = wri[0]; int fs = wrslot[0];
            #pragma unroll
            for (int ww = 1; ww < 4; ++ww)
                if (pri_gt(wrs[ww], wri[ww], fv, fi)) {
                    fv = wrs[ww]; fi = wri[ww]; fs = wrslot[ww];
                }
            out[q * KTOP + r]                     = (float)fi;
            out[(size_t)BQ * KTOP + q * KTOP + r] = fv;
            Ls[fs] = NEG_INF; Li[fs] = 0x7fffffff;
        }
        __syncthreads();
    }
}

// ---------------------------------------------------------------------------
extern "C" void kernel_launch(void* const* d_in, const int* in_sizes, int n_in,
                              void* d_out, int out_size, void* d_ws, size_t ws_size,
                              hipStream_t stream)
{
    const float* Qf   = (const float*)d_in[0];
    const float* G    = (const float*)d_in[1];
    const int*   mask = (const int*)d_in[2];
    const int Ntot = in_sizes[1] / DK;                 // 200000

    const int NCH = (Ntot + CHI - 1) / CHI;            // 6250
    int SC = GRIDP * NSAMP;                            // 768 sampled chunks
    if (SC > NCH) SC = NCH;

    // ws layout (bytes): ~10 MB total
    char* w = (char*)d_ws;
    int*   ocnt = (int*)(w + 0);                       // [0,4096) control
    float* thrm = (float*)(w + 4096);                  // 512 B
    float* gmax = (float*)(w + 8192);                  // SC*128*4
    size_t off = 8192 + (size_t)SC * BQ * 4;
    off = (off + 255) & ~(size_t)255;
    int*   cnt2 = (int*)(w + off);                     // 128*NCH*4
    off += (size_t)BQ * NCH * 4; off = (off + 255) & ~(size_t)255;
    float* cs   = (float*)(w + off);                   // 128*NCH*SLOTS*4
    off += (size_t)BQ * NCH * SLOTS * 4;
    int*   ci   = (int*)(w + off);
    off += (size_t)BQ * NCH * SLOTS * 4;
    int*   oqv  = (int*)(w + off);   off += (size_t)OCAP * 4;
    int*   ogv  = (int*)(w + off);   off += (size_t)OCAP * 4;
    float* osv  = (float*)(w + off);

    (void)hipMemsetAsync(w, 0, 4096, stream);
    score_pass<0><<<dim3(GRIDP), dim3(256), 0, stream>>>(   // sampled maxima
        Qf, G, mask, thrm, gmax, cnt2, cs, ci, ocnt, oqv, ogv, osv,
        Ntot, NCH, SC);
    thr32<<<dim3(BQ), dim3(256), 0, stream>>>(gmax, thrm, SC);
    score_pass<1><<<dim3(GRIDP), dim3(256), 0, stream>>>(   // full filter
        Qf, G, mask, thrm, gmax, cnt2, cs, ci, ocnt, oqv, ogv, osv,
        Ntot, NCH, SC);
    select_topk<<<dim3(BQ), dim3(256), 0, stream>>>(
        cs, ci, cnt2, ocnt, oqv, ogv, osv, (float*)d_out, NCH);
}

// Round 14
// 235.870 us; speedup vs baseline: 1.2336x; 1.2336x over previous
//
#include <hip/hip_runtime.h>
#include <hip/hip_bf16.h>
#include <cstdint>
#include <cstddef>

#define BQ 128        // queries (problem-fixed)
#define DK 192        // SIG_DIM
#define KTOP 32
#define CHI 32        // gallery items per chunk
#define SLOTS 2       // candidate slots per (query, chunk)
#define QCAP 512      // per-chunk LDS rescore queue
#define OCAP 65536    // global overflow list
#define MARGIN 0.02f  // > 2x (trunc-G + rne-Q) dot error bound (~0.012)
#define SCN 768       // sampled chunks for threshold
#define THRV 3200     // thr32 LDS value slots
#define CNTL 6400     // select: LDS-cached per-chunk counts

#define NEG_INF (-__builtin_huge_valf())

typedef short short8v __attribute__((ext_vector_type(8)));
typedef float f32x16  __attribute__((ext_vector_type(16)));

__device__ __forceinline__ unsigned fkey(float s) {
    unsigned u = __float_as_uint(s);
    return (u & 0x80000000u) ? ~u : (u | 0x80000000u);   // monotone f32 -> u32
}
__device__ __forceinline__ bool pri_gt(float s1, int i1, float s2, int i2) {
    return (s1 > s2) || (s1 == s2 && i1 < i2);           // jax top_k stability
}
// pack {bf16_trunc(b) : bf16_trunc(a)} in one v_perm_b32 (high halves)
__device__ __forceinline__ unsigned pk_trunc(float a, float b) {
    return __builtin_amdgcn_perm(__float_as_uint(b), __float_as_uint(a),
                                 0x07060302u);
}
__device__ __forceinline__ unsigned f2bf_rne(float x) {
    unsigned u = __float_as_uint(x);
    unsigned r = u + 0x7FFFu + ((u >> 16) & 1u);
    return r >> 16;
}
__device__ __forceinline__ float dot192(const float* __restrict__ a,
                                        const float* __restrict__ b) {
    float s = 0.f;
    #pragma unroll 8
    for (int k = 0; k < DK; ++k) s = fmaf(a[k], b[k], s);
    return s;
}
// async global->LDS DMA, 16B/lane; LDS base wave-uniform (HW adds lane*16)
__device__ __forceinline__ void gload_lds16(const void* g, void* l) {
    __builtin_amdgcn_global_load_lds(
        (const __attribute__((address_space(1))) unsigned int*)g,
        (__attribute__((address_space(3))) unsigned int*)l,
        16, 0, 0);
}

// ---------------------------------------------------------------------------
// qprep: build the 48 KB bf16 Q image in ws, pre-swizzled so score_pass can
// DMA it straight into LDS. Image block (row, c) holds Q row's block c^(row&7).
// ---------------------------------------------------------------------------
__global__ __launch_bounds__(256) void qprep(
    const float* __restrict__ Qf, unsigned char* __restrict__ Qb)
{
    const int blk = blockIdx.x * 256 + threadIdx.x;      // 3072 16B-blocks
    if (blk >= BQ * 24) return;
    const int row = blk / 24, c = blk - row * 24;
    const int csrc = c ^ (row & 7);                      // pre-swizzle source
    const float* qp = Qf + row * DK + csrc * 8;
    float4 x = *reinterpret_cast<const float4*>(qp);
    float4 y = *reinterpret_cast<const float4*>(qp + 4);
    uint4 p;
    p.x = f2bf_rne(x.x) | (f2bf_rne(x.y) << 16);
    p.y = f2bf_rne(x.z) | (f2bf_rne(x.w) << 16);
    p.z = f2bf_rne(y.x) | (f2bf_rne(y.y) << 16);
    p.w = f2bf_rne(y.z) | (f2bf_rne(y.w) << 16);
    *reinterpret_cast<uint4*>(Qb + (size_t)blk * 16) = p;
}

// ---------------------------------------------------------------------------
// Straight-line MFMA scoring block: ONE 32-item chunk x all 128 queries.
// No loops carrying state -> nothing for the allocator to hoist/spill
// (r10-r13 killer). Q (48 KB, L2-hot) and G (24 KB, HBM) both arrive via
// global_load_lds DMA; one barrier; 12 x {2 ds_read + MFMA}; epilogue.
// LDS ~75 KB -> 2 blocks/CU: the co-resident block's compute covers this
// block's DMA drain.
// MODE 0: masked per-(chunk,q) bf16 max -> gmax[blockIdx][q]
// MODE 1: threshold filter -> LDS queue -> exact fp32 rescore -> slotted store
// ---------------------------------------------------------------------------
template<int MODE>
__global__ __launch_bounds__(256) void score_pass(
    const float* __restrict__ Qf, const unsigned char* __restrict__ Qb,
    const float* __restrict__ G,
    const int* __restrict__ mask, const float* __restrict__ thrm,
    float* __restrict__ gmax,
    int* __restrict__ cnt2, float* __restrict__ cs, int* __restrict__ ci,
    int* __restrict__ ocnt, int* __restrict__ oq, int* __restrict__ og,
    float* __restrict__ osv,
    int Ntot, int NCH, int SC)
{
    __shared__ unsigned char Qlds[BQ * 384];   // 48 KB bf16 Q (swizzled image)
    __shared__ float    Gf[CHI * DK];          // 24 KB fp32 G tile
    __shared__ float    thrmS[BQ];
    __shared__ unsigned queue[QCAP];
    __shared__ int      lcnt[BQ];
    __shared__ int      qn;

    const int t = threadIdx.x;
    const int w = t >> 6, lane = t & 63;
    const int lo5 = lane & 31, hi = lane >> 5;
    const int qbW = w * 32;

    const int chunk = (MODE == 0)
        ? (int)(((long long)blockIdx.x * NCH) / SC)      // strided sample
        : (int)blockIdx.x;
    const int cb = chunk * CHI;

    // ---- issue G DMA first (HBM, the long pole): 6 insts, swizzled source
    {
        #pragma unroll
        for (int i = 0; i < 6; ++i) {
            const int slot = t + (i << 8);
            const int r = slot / 48, c = slot - r * 48;
            size_t grow = (size_t)cb + r;
            if (grow >= (size_t)Ntot) grow = (size_t)Ntot - 1;   // safe dup
            const char* gp = (const char*)G + grow * (DK * 4)
                           + ((c ^ (r & 7)) << 4);
            char* lp = (char*)Gf + ((i << 2) + w) * 1024;        // wave-uniform
            gload_lds16(gp, lp);
        }
    }
    // ---- Q DMA: straight 48 KB memcpy of the pre-swizzled image (L2-hot)
    {
        #pragma unroll
        for (int i = 0; i < 12; ++i) {
            const unsigned off = (unsigned)(((i << 2) + w) * 1024);
            const char* gp = (const char*)Qb + off + lane * 16;
            char* lp = (char*)Qlds + off;                        // wave-uniform
            gload_lds16(gp, lp);
        }
    }
    if (t < BQ) { thrmS[t] = (MODE == 1) ? thrm[t] : 0.f; lcnt[t] = 0; }
    if (t == 0) qn = 0;
    __syncthreads();                     // drains both DMAs (vmcnt before barrier)

    const unsigned xsh = (unsigned)((lo5 & 7) << 4);
    const unsigned abase = (unsigned)((qbW + lo5) * 384);
    const char* rowp = (const char*)Gf + lo5 * (DK * 4);

    f32x16 acc = {0,0,0,0,0,0,0,0,0,0,0,0,0,0,0,0};
    #pragma unroll
    for (int s = 0; s < 12; ++s) {
        union { uint4 u; short8v v; } au;
        au.u = *reinterpret_cast<const uint4*>(
            Qlds + abase + ((unsigned)(((s << 1) + hi) << 4) ^ xsh));
        const unsigned b0 = ((unsigned)((s * 4 + hi * 2) << 4)) ^ xsh;
        const unsigned b1 = ((unsigned)((s * 4 + hi * 2 + 1) << 4)) ^ xsh;
        float4 f0 = *reinterpret_cast<const float4*>(rowp + b0);
        float4 f1 = *reinterpret_cast<const float4*>(rowp + b1);
        union { unsigned u[4]; short8v v; } bu;
        bu.u[0] = pk_trunc(f0.x, f0.y); bu.u[1] = pk_trunc(f0.z, f0.w);
        bu.u[2] = pk_trunc(f1.x, f1.y); bu.u[3] = pk_trunc(f1.z, f1.w);
        acc = __builtin_amdgcn_mfma_f32_32x32x16_bf16(au.v, bu.v, acc, 0, 0, 0);
    }

    // C layout (32x32): col(item)=lane&31, row(query)=(j&3)+8*(j>>2)+4*hi
    if (MODE == 0) {
        #pragma unroll
        for (int j = 0; j < 16; ++j) {
            const int row = (j & 3) + 8 * (j >> 2) + 4 * hi;
            const int q = qbW + row;
            const int g = cb + lo5;
            float m = NEG_INF;
            if (g < Ntot && !mask[(size_t)q * (size_t)Ntot + g])
                m = acc[j];
            #pragma unroll
            for (int off = 1; off < 32; off <<= 1)
                m = fmaxf(m, __shfl_xor(m, off));
            if (lo5 == 0) gmax[(size_t)blockIdx.x * BQ + q] = m;
        }
    } else {
        #pragma unroll
        for (int j = 0; j < 16; ++j) {
            const int row = (j & 3) + 8 * (j >> 2) + 4 * hi;
            const int q = qbW + row;
            const float th = thrmS[q];
            const int g = cb + lo5;
            const float s = acc[j];
            if (g < Ntot && s >= th) {
                if (!mask[(size_t)q * (size_t)Ntot + g]) {
                    const int p = atomicAdd(&qn, 1);
                    if (p < QCAP) {
                        queue[p] = ((unsigned)q << 24) | (unsigned)g;
                    } else {   // pathological: inline exact rescore
                        float sx = dot192(Qf + q * DK, G + (size_t)g * DK);
                        const int op = atomicAdd(ocnt, 1);
                        if (op < OCAP) { oq[op] = q; og[op] = g; osv[op] = sx; }
                    }
                }
            }
        }
        __syncthreads();
        const int nq = qn < QCAP ? qn : QCAP;
        for (int cc = w; cc < nq; cc += 4) {       // one wave per candidate
            const unsigned pk = queue[cc];
            const int q = pk >> 24, g = pk & 0xFFFFFF;
            const float* qr = Qf + q * DK;
            const float* gr = G + (size_t)g * DK;
            const int k0 = lane * 3;
            float part = qr[k0] * gr[k0];
            part = fmaf(qr[k0 + 1], gr[k0 + 1], part);
            part = fmaf(qr[k0 + 2], gr[k0 + 2], part);
            #pragma unroll
            for (int off = 32; off > 0; off >>= 1)
                part += __shfl_xor(part, off);
            if (lane == 0) {
                const int p = atomicAdd(&lcnt[q], 1);
                if (p < SLOTS) {
                    const size_t o = ((size_t)q * NCH + chunk) * SLOTS + p;
                    cs[o] = part; ci[o] = g;
                } else {
                    const int op = atomicAdd(ocnt, 1);
                    if (op < OCAP) { oq[op] = q; og[op] = g; osv[op] = part; }
                }
            }
        }
        __syncthreads();
        if (t < BQ) {
            int v = lcnt[t]; if (v > SLOTS) v = SLOTS;
            cnt2[(size_t)t * NCH + chunk] = v;
        }
    }
}

// ---------------------------------------------------------------------------
// thrm[q] = (exact 32nd-largest of SC sampled masked chunk-maxima) - MARGIN.
// Valid bound: 32 distinct unmasked witnesses with bf16 score >= thr.
// ---------------------------------------------------------------------------
__global__ __launch_bounds__(256) void thr32(
    const float* __restrict__ gmax, float* __restrict__ thrm, int SC)
{
    __shared__ float vals[THRV];
    __shared__ int hist[256];
    __shared__ int hscan[256];
    __shared__ int bS, gtS;

    const int q = blockIdx.x;
    const int t = threadIdx.x;
    const int M = SC < THRV ? SC : THRV;

    for (int i = t; i < M; i += 256) {
        float m = gmax[(size_t)i * BQ + q];
        for (int j = i + THRV; j < SC; j += THRV)
            m = fmaxf(m, gmax[(size_t)j * BQ + q]);
        vals[i] = m;
    }
    __syncthreads();

    unsigned prefix = 0, pmask = 0;
    int kneed = KTOP;
    for (int pass = 0; pass < 4; ++pass) {
        const int shift = 24 - pass * 8;
        hist[t] = 0;
        __syncthreads();
        for (int i = t; i < M; i += 256) {
            unsigned k = fkey(vals[i]);
            if ((k & pmask) == prefix) atomicAdd(&hist[(k >> shift) & 255], 1);
        }
        __syncthreads();
        int* src = hist; int* dst = hscan;
        for (int off = 1; off < 256; off <<= 1) {
            int v = src[t] + ((t + off) < 256 ? src[t + off] : 0);
            __syncthreads();
            dst[t] = v;
            __syncthreads();
            int* tmp = src; src = dst; dst = tmp;
        }
        if (src[t] >= kneed && (t == 255 || src[t + 1] < kneed)) {
            bS = t; gtS = (t == 255) ? 0 : src[t + 1];
        }
        __syncthreads();
        kneed -= gtS;
        prefix |= ((unsigned)bS) << shift;
        pmask  |= 0xFFu << shift;
        __syncthreads();
    }
    if (t == 0) {
        unsigned u = (prefix & 0x80000000u) ? (prefix & 0x7FFFFFFFu) : ~prefix;
        thrm[q] = __uint_as_float(u) - MARGIN;
    }
}

// ---------------------------------------------------------------------------
// Exact per-query top-32 over slotted candidates (+overflow): 4-pass radix
// select + collect + tie-breaking tournament (score desc, idx asc).
// out: [0..B*K) = indices (as float); [B*K..2BK) = scores.
// ---------------------------------------------------------------------------
__global__ __launch_bounds__(256) void select_topk(
    const float* __restrict__ cs, const int* __restrict__ ci,
    const int* __restrict__ cnt2,
    const int* __restrict__ ocnt, const int* __restrict__ oq,
    const int* __restrict__ og, const float* __restrict__ osv,
    float* __restrict__ out, int CBLK)
{
    __shared__ int   cntRow[CNTL];
    __shared__ int   hist[256];
    __shared__ int   hscan[256];
    __shared__ float Ls[256];
    __shared__ int   Li[256];
    __shared__ int   lcnt, nTotS, bS, gtS;
    __shared__ float wrs[4]; __shared__ int wri[4], wrslot[4];

    const int q = blockIdx.x;
    const int t = threadIdx.x;
    const size_t qbase = (size_t)q * CBLK * SLOTS;
    const size_t cbase = (size_t)q * CBLK;
    const int CC = CBLK < CNTL ? CBLK : CNTL;
    const int novf0 = *ocnt;
    const int novf = novf0 < OCAP ? novf0 : OCAP;
    const int nslots = CBLK * SLOTS;

    for (int i = t; i < CC; i += 256) cntRow[i] = cnt2[cbase + i];
    if (t == 0) nTotS = 0;
    __syncthreads();
    {
        int part = 0;
        for (int i = t; i < CBLK; i += 256)
            part += (i < CNTL) ? cntRow[i] : cnt2[cbase + i];
        for (int i = t; i < novf; i += 256)
            if (oq[i] == q) part++;
        atomicAdd(&nTotS, part);
    }
    __syncthreads();
    const int nTot = nTotS;

    unsigned prefix = 0, pmask = 0;
    int kneed = KTOP;

    if (nTot > KTOP) {
        for (int pass = 0; pass < 4; ++pass) {
            const int shift = 24 - pass * 8;
            hist[t] = 0;
            __syncthreads();
            for (int i = t; i < nslots; i += 256) {
                const int b = i >> 1, sl = i & 1;          // SLOTS = 2
                const int cb = (b < CNTL) ? cntRow[b] : cnt2[cbase + b];
                if (sl < cb) {
                    unsigned k = fkey(cs[qbase + i]);
                    if ((k & pmask) == prefix)
                        atomicAdd(&hist[(k >> shift) & 255], 1);
                }
            }
            for (int i = t; i < novf; i += 256) {
                if (oq[i] == q) {
                    unsigned k = fkey(osv[i]);
                    if ((k & pmask) == prefix)
                        atomicAdd(&hist[(k >> shift) & 255], 1);
                }
            }
            __syncthreads();
            int* src = hist; int* dst = hscan;
            for (int off = 1; off < 256; off <<= 1) {
                int v = src[t] + ((t + off) < 256 ? src[t + off] : 0);
                __syncthreads();
                dst[t] = v;
                __syncthreads();
                int* tmp = src; src = dst; dst = tmp;
            }
            if (src[t] >= kneed && (t == 255 || src[t + 1] < kneed)) {
                bS = t;
                gtS = (t == 255) ? 0 : src[t + 1];
            }
            __syncthreads();
            const int b = bS;
            kneed -= gtS;
            prefix |= ((unsigned)b) << shift;
            pmask  |= 0xFFu << shift;
            __syncthreads();
        }
    }

    if (t == 0) lcnt = 0;
    __syncthreads();
    const unsigned T = (nTot > KTOP) ? prefix : 0u;
    for (int i = t; i < nslots; i += 256) {
        const int b = i >> 1, sl = i & 1;
        const int cb = (b < CNTL) ? cntRow[b] : cnt2[cbase + b];
        if (sl < cb) {
            float s = cs[qbase + i];
            if (fkey(s) >= T) {
                int p = atomicAdd(&lcnt, 1);
                if (p < 256) { Ls[p] = s; Li[p] = ci[qbase + i]; }
            }
        }
    }
    for (int i = t; i < novf; i += 256) {
        if (oq[i] == q) {
            float s = osv[i];
            if (fkey(s) >= T) {
                int p = atomicAdd(&lcnt, 1);
                if (p < 256) { Ls[p] = s; Li[p] = og[i]; }
            }
        }
    }
    __syncthreads();
    const int M = lcnt < 256 ? lcnt : 256;

    const int w = t >> 6, lane = t & 63;
    for (int r = 0; r < KTOP; ++r) {
        float bv = (t < M) ? Ls[t] : NEG_INF;
        int   bi = (t < M) ? Li[t] : 0x7fffffff;
        int   bslot = t;
        #pragma unroll
        for (int off = 32; off > 0; off >>= 1) {
            float ov = __shfl_xor(bv, off);
            int   oi = __shfl_xor(bi, off);
            int   osl = __shfl_xor(bslot, off);
            if (pri_gt(ov, oi, bv, bi)) { bv = ov; bi = oi; bslot = osl; }
        }
        if (lane == 0) { wrs[w] = bv; wri[w] = bi; wrslot[w] = bslot; }
        __syncthreads();
        if (t == 0) {
            float fv = wrs[0]; int fi = wri[0]; int fs = wrslot[0];
            #pragma unroll
            for (int ww = 1; ww < 4; ++ww)
                if (pri_gt(wrs[ww], wri[ww], fv, fi)) {
                    fv = wrs[ww]; fi = wri[ww]; fs = wrslot[ww];
                }
            out[q * KTOP + r]                     = (float)fi;
            out[(size_t)BQ * KTOP + q * KTOP + r] = fv;
            Ls[fs] = NEG_INF; Li[fs] = 0x7fffffff;
        }
        __syncthreads();
    }
}

// ---------------------------------------------------------------------------
extern "C" void kernel_launch(void* const* d_in, const int* in_sizes, int n_in,
                              void* d_out, int out_size, void* d_ws, size_t ws_size,
                              hipStream_t stream)
{
    const float* Qf   = (const float*)d_in[0];
    const float* G    = (const float*)d_in[1];
    const int*   mask = (const int*)d_in[2];
    const int Ntot = in_sizes[1] / DK;                 // 200000

    const int NCH = (Ntot + CHI - 1) / CHI;            // 6250
    int SC = SCN;                                      // 768 sampled chunks
    if (SC > NCH) SC = NCH;

    // ws layout (bytes): ~10 MB total
    char* w = (char*)d_ws;
    int*   ocnt = (int*)(w + 0);                       // [0,4096) control
    float* thrm = (float*)(w + 4096);                  // 512 B
    unsigned char* Qb = (unsigned char*)(w + 8192);    // 48 KB Q image
    size_t off = 8192 + (size_t)BQ * 384;
    off = (off + 255) & ~(size_t)255;
    float* gmax = (float*)(w + off);                   // SC*128*4
    off += (size_t)SC * BQ * 4; off = (off + 255) & ~(size_t)255;
    int*   cnt2 = (int*)(w + off);                     // 128*NCH*4
    off += (size_t)BQ * NCH * 4; off = (off + 255) & ~(size_t)255;
    float* cs   = (float*)(w + off);                   // 128*NCH*SLOTS*4
    off += (size_t)BQ * NCH * SLOTS * 4;
    int*   ci   = (int*)(w + off);
    off += (size_t)BQ * NCH * SLOTS * 4;
    int*   oqv  = (int*)(w + off);   off += (size_t)OCAP * 4;
    int*   ogv  = (int*)(w + off);   off += (size_t)OCAP * 4;
    float* osv  = (float*)(w + off);

    (void)hipMemsetAsync(w, 0, 4096, stream);
    qprep<<<dim3((BQ * 24 + 255) / 256), dim3(256), 0, stream>>>(Qf, Qb);
    score_pass<0><<<dim3(SC), dim3(256), 0, stream>>>(      // sampled maxima
        Qf, Qb, G, mask, thrm, gmax, cnt2, cs, ci, ocnt, oqv, ogv, osv,
        Ntot, NCH, SC);
    thr32<<<dim3(BQ), dim3(256), 0, stream>>>(gmax, thrm, SC);
    score_pass<1><<<dim3(NCH), dim3(256), 0, stream>>>(     // full filter
        Qf, Qb, G, mask, thrm, gmax, cnt2, cs, ci, ocnt, oqv, ogv, osv,
        Ntot, NCH, SC);
    select_topk<<<dim3(BQ), dim3(256), 0, stream>>>(
        cs, ci, cnt2, ocnt, oqv, ogv, osv, (float*)d_out, NCH);
}

// Round 15
// 196.104 us; speedup vs baseline: 1.4838x; 1.2028x over previous
//
#include <hip/hip_runtime.h>
#include <hip/hip_bf16.h>
#include <cstdint>
#include <cstddef>

#define BQ 128        // queries (problem-fixed)
#define DK 192        // SIG_DIM
#define KTOP 32
#define CHI 32        // gallery items per chunk (one chunk per block)
#define QCAP 512      // per-block LDS rescore queue
#define CAP 8192      // dense candidate list capacity per query
#define OCAP 65536    // global overflow list
#define MARGIN 0.02f  // > 2x (trunc-G + rne-Q) dot error bound (~0.012)
#define SCN 768       // sampled chunks for threshold
#define THRV 3200     // thr32 LDS value slots

#define NEG_INF (-__builtin_huge_valf())

typedef short short8v __attribute__((ext_vector_type(8)));
typedef float f32x16  __attribute__((ext_vector_type(16)));

__device__ __forceinline__ unsigned fkey(float s) {
    unsigned u = __float_as_uint(s);
    return (u & 0x80000000u) ? ~u : (u | 0x80000000u);   // monotone f32 -> u32
}
__device__ __forceinline__ bool pri_gt(float s1, int i1, float s2, int i2) {
    return (s1 > s2) || (s1 == s2 && i1 < i2);           // jax top_k stability
}
// pack {bf16_trunc(b) : bf16_trunc(a)} in one v_perm_b32 (high halves)
__device__ __forceinline__ unsigned pk_trunc(float a, float b) {
    return __builtin_amdgcn_perm(__float_as_uint(b), __float_as_uint(a),
                                 0x07060302u);
}
__device__ __forceinline__ unsigned f2bf_rne(float x) {
    unsigned u = __float_as_uint(x);
    unsigned r = u + 0x7FFFu + ((u >> 16) & 1u);
    return r >> 16;
}
__device__ __forceinline__ float dot192(const float* __restrict__ a,
                                        const float* __restrict__ b) {
    float s = 0.f;
    #pragma unroll 8
    for (int k = 0; k < DK; ++k) s = fmaf(a[k], b[k], s);
    return s;
}

// ---------------------------------------------------------------------------
// qprep: Q fp32 -> bf16 row-major image (RNE) in ws. 24576 elems.
// ---------------------------------------------------------------------------
__global__ __launch_bounds__(256) void qprep(
    const float* __restrict__ Qf, unsigned short* __restrict__ Qb)
{
    const int i = blockIdx.x * 256 + threadIdx.x;
    if (i < BQ * DK) Qb[i] = (unsigned short)f2bf_rne(Qf[i]);
}

// ---------------------------------------------------------------------------
// LDS-free MFMA scoring: D[item][q] = mfma(A = G rows, B = Q cols).
// A-fragment: lane = item row (lane&31), k = (lane>>5)*8.. -> 2 float4 G loads
// B-fragment: lane = query col (lane&31), same k -> 1 uint4 load of bf16 Q
// Both direct from row-major memory: no LDS operands, no staging barriers.
// Each wave owns 32 queries (w*32..+31) x the block's 32-item chunk.
// MODE 0: masked per-(chunk,q) bf16 max -> gmax[blockIdx][q]  (sampled)
// MODE 1: threshold filter -> LDS queue -> exact fp32 wave-rescore ->
//         dense per-q list via line-padded global counter (gcnt stride 16)
// __launch_bounds__(256,4): VGPR cap 128 >> ~60 live => no spills.
// ---------------------------------------------------------------------------
template<int MODE>
__global__ __launch_bounds__(256, 4) void score_pass(
    const float* __restrict__ Qf, const unsigned short* __restrict__ Qb,
    const float* __restrict__ G,
    const int* __restrict__ mask, const float* __restrict__ thrm,
    float* __restrict__ gmax,
    int* __restrict__ gcnt, float* __restrict__ cs, int* __restrict__ ci,
    int* __restrict__ ocnt, int* __restrict__ oq, int* __restrict__ og,
    float* __restrict__ osv,
    int Ntot, int NCH, int SC)
{
    __shared__ unsigned queue[QCAP];
    __shared__ int qn;

    const int t = threadIdx.x;
    const int w = t >> 6, lane = t & 63;
    const int lo5 = lane & 31, hi = lane >> 5;
    const int myq = w * 32 + lo5;                 // this lane's query column

    const int chunk = (MODE == 0)
        ? (int)(((long long)blockIdx.x * NCH) / SC)
        : (int)blockIdx.x;
    const int cb = chunk * CHI;

    if (t == 0) qn = 0;
    __syncthreads();

    const float th = (MODE == 1) ? thrm[myq] : 0.f;

    int grow = cb + lo5; if (grow >= Ntot) grow = Ntot - 1;   // safe dup row
    const float* gp = G + (size_t)grow * DK + hi * 8;
    const unsigned short* qp = Qb + (size_t)myq * DK + hi * 8;

    f32x16 acc = {0,0,0,0,0,0,0,0,0,0,0,0,0,0,0,0};
    #pragma unroll
    for (int s = 0; s < 12; ++s) {
        float4 f0 = *reinterpret_cast<const float4*>(gp + s * 16);
        float4 f1 = *reinterpret_cast<const float4*>(gp + s * 16 + 4);
        union { unsigned u[4]; short8v v; } av;
        av.u[0] = pk_trunc(f0.x, f0.y); av.u[1] = pk_trunc(f0.z, f0.w);
        av.u[2] = pk_trunc(f1.x, f1.y); av.u[3] = pk_trunc(f1.z, f1.w);
        union { uint4 u; short8v v; } bv;
        bv.u = *reinterpret_cast<const uint4*>(qp + s * 16);
        acc = __builtin_amdgcn_mfma_f32_32x32x16_bf16(av.v, bv.v, acc, 0, 0, 0);
    }

    // D layout: row(item) = (j&3)+8*(j>>2)+4*hi, col(q) = lane&31
    const size_t mrow = (size_t)myq * (size_t)Ntot;
    if (MODE == 0) {
        float m = NEG_INF;
        #pragma unroll
        for (int j = 0; j < 16; ++j) {
            const int g = cb + ((j & 3) + 8 * (j >> 2) + 4 * hi);
            if (g < Ntot && !mask[mrow + g]) m = fmaxf(m, acc[j]);
        }
        m = fmaxf(m, __shfl_xor(m, 32));          // combine hi halves
        if (hi == 0) gmax[(size_t)blockIdx.x * BQ + myq] = m;
    } else {
        #pragma unroll
        for (int j = 0; j < 16; ++j) {
            const int g = cb + ((j & 3) + 8 * (j >> 2) + 4 * hi);
            const float s = acc[j];
            if (g < Ntot && s >= th) {
                if (!mask[mrow + g]) {
                    const int p = atomicAdd(&qn, 1);
                    if (p < QCAP) {
                        queue[p] = ((unsigned)myq << 24) | (unsigned)g;
                    } else {   // pathological: inline exact rescore
                        float sx = dot192(Qf + myq * DK, G + (size_t)g * DK);
                        const int op = atomicAdd(ocnt, 1);
                        if (op < OCAP) { oq[op] = myq; og[op] = g; osv[op] = sx; }
                    }
                }
            }
        }
        __syncthreads();
        const int nq = qn < QCAP ? qn : QCAP;
        for (int cc = w; cc < nq; cc += 4) {       // one wave per candidate
            const unsigned pk = queue[cc];
            const int q = pk >> 24, g = pk & 0xFFFFFF;
            const float* qr = Qf + q * DK;
            const float* gr = G + (size_t)g * DK;
            const int k0 = lane * 3;
            float part = qr[k0] * gr[k0];
            part = fmaf(qr[k0 + 1], gr[k0 + 1], part);
            part = fmaf(qr[k0 + 2], gr[k0 + 2], part);
            #pragma unroll
            for (int off = 32; off > 0; off >>= 1)
                part += __shfl_xor(part, off);
            if (lane == 0) {
                const int pos = atomicAdd(&gcnt[q * 16], 1);   // 64B-padded ctr
                if (pos < CAP) {
                    cs[(size_t)q * CAP + pos] = part;
                    ci[(size_t)q * CAP + pos] = g;
                } else {
                    const int op = atomicAdd(ocnt, 1);
                    if (op < OCAP) { oq[op] = q; og[op] = g; osv[op] = part; }
                }
            }
        }
    }
}

// ---------------------------------------------------------------------------
// thrm[q] = (exact 32nd-largest of SC sampled masked chunk-maxima) - MARGIN.
// Valid bound: 32 distinct unmasked witnesses with bf16 score >= thr.
// ---------------------------------------------------------------------------
__global__ __launch_bounds__(256) void thr32(
    const float* __restrict__ gmax, float* __restrict__ thrm, int SC)
{
    __shared__ float vals[THRV];
    __shared__ int hist[256];
    __shared__ int hscan[256];
    __shared__ int bS, gtS;

    const int q = blockIdx.x;
    const int t = threadIdx.x;
    const int M = SC < THRV ? SC : THRV;

    for (int i = t; i < M; i += 256) {
        float m = gmax[(size_t)i * BQ + q];
        for (int j = i + THRV; j < SC; j += THRV)
            m = fmaxf(m, gmax[(size_t)j * BQ + q]);
        vals[i] = m;
    }
    __syncthreads();

    unsigned prefix = 0, pmask = 0;
    int kneed = KTOP;
    for (int pass = 0; pass < 4; ++pass) {
        const int shift = 24 - pass * 8;
        hist[t] = 0;
        __syncthreads();
        for (int i = t; i < M; i += 256) {
            unsigned k = fkey(vals[i]);
            if ((k & pmask) == prefix) atomicAdd(&hist[(k >> shift) & 255], 1);
        }
        __syncthreads();
        int* src = hist; int* dst = hscan;
        for (int off = 1; off < 256; off <<= 1) {
            int v = src[t] + ((t + off) < 256 ? src[t + off] : 0);
            __syncthreads();
            dst[t] = v;
            __syncthreads();
            int* tmp = src; src = dst; dst = tmp;
        }
        if (src[t] >= kneed && (t == 255 || src[t + 1] < kneed)) {
            bS = t; gtS = (t == 255) ? 0 : src[t + 1];
        }
        __syncthreads();
        kneed -= gtS;
        prefix |= ((unsigned)bS) << shift;
        pmask  |= 0xFFu << shift;
        __syncthreads();
    }
    if (t == 0) {
        unsigned u = (prefix & 0x80000000u) ? (prefix & 0x7FFFFFFFu) : ~prefix;
        thrm[q] = __uint_as_float(u) - MARGIN;
    }
}

// ---------------------------------------------------------------------------
// Exact per-query top-32 over dense candidate list (+overflow): 4-pass radix
// select + collect + tie-breaking tournament (score desc, idx asc).
// out: [0..B*K) = indices (as float); [B*K..2BK) = scores.
// ---------------------------------------------------------------------------
__global__ __launch_bounds__(256) void select_topk(
    const float* __restrict__ cs, const int* __restrict__ ci,
    const int* __restrict__ gcnt,
    const int* __restrict__ ocnt, const int* __restrict__ oq,
    const int* __restrict__ og, const float* __restrict__ osv,
    float* __restrict__ out)
{
    __shared__ int   hist[256];
    __shared__ int   hscan[256];
    __shared__ float Ls[256];
    __shared__ int   Li[256];
    __shared__ int   lcnt, nTotS, bS, gtS;
    __shared__ float wrs[4]; __shared__ int wri[4], wrslot[4];

    const int q = blockIdx.x;
    const int t = threadIdx.x;
    const int n0 = gcnt[q * 16];
    const int n = n0 < CAP ? n0 : CAP;
    const size_t base = (size_t)q * CAP;
    const int novf0 = *ocnt;
    const int novf = novf0 < OCAP ? novf0 : OCAP;

    if (t == 0) nTotS = 0;
    __syncthreads();
    {
        int part = (t == 0) ? n : 0;
        for (int i = t; i < novf; i += 256)
            if (oq[i] == q) part++;
        atomicAdd(&nTotS, part);
    }
    __syncthreads();
    const int nTot = nTotS;

    unsigned prefix = 0, pmask = 0;
    int kneed = KTOP;

    if (nTot > KTOP) {
        for (int pass = 0; pass < 4; ++pass) {
            const int shift = 24 - pass * 8;
            hist[t] = 0;
            __syncthreads();
            for (int i = t; i < n; i += 256) {
                unsigned k = fkey(cs[base + i]);
                if ((k & pmask) == prefix)
                    atomicAdd(&hist[(k >> shift) & 255], 1);
            }
            for (int i = t; i < novf; i += 256) {
                if (oq[i] == q) {
                    unsigned k = fkey(osv[i]);
                    if ((k & pmask) == prefix)
                        atomicAdd(&hist[(k >> shift) & 255], 1);
                }
            }
            __syncthreads();
            int* src = hist; int* dst = hscan;
            for (int off = 1; off < 256; off <<= 1) {
                int v = src[t] + ((t + off) < 256 ? src[t + off] : 0);
                __syncthreads();
                dst[t] = v;
                __syncthreads();
                int* tmp = src; src = dst; dst = tmp;
            }
            if (src[t] >= kneed && (t == 255 || src[t + 1] < kneed)) {
                bS = t;
                gtS = (t == 255) ? 0 : src[t + 1];
            }
            __syncthreads();
            const int b = bS;
            kneed -= gtS;
            prefix |= ((unsigned)b) << shift;
            pmask  |= 0xFFu << shift;
            __syncthreads();
        }
    }

    if (t == 0) lcnt = 0;
    __syncthreads();
    const unsigned T = (nTot > KTOP) ? prefix : 0u;
    for (int i = t; i < n; i += 256) {
        float s = cs[base + i];
        if (fkey(s) >= T) {
            int p = atomicAdd(&lcnt, 1);
            if (p < 256) { Ls[p] = s; Li[p] = ci[base + i]; }
        }
    }
    for (int i = t; i < novf; i += 256) {
        if (oq[i] == q) {
            float s = osv[i];
            if (fkey(s) >= T) {
                int p = atomicAdd(&lcnt, 1);
                if (p < 256) { Ls[p] = s; Li[p] = og[i]; }
            }
        }
    }
    __syncthreads();
    const int M = lcnt < 256 ? lcnt : 256;

    const int w = t >> 6, lane = t & 63;
    for (int r = 0; r < KTOP; ++r) {
        float bv = (t < M) ? Ls[t] : NEG_INF;
        int   bi = (t < M) ? Li[t] : 0x7fffffff;
        int   bslot = t;
        #pragma unroll
        for (int off = 32; off > 0; off >>= 1) {
            float ov = __shfl_xor(bv, off);
            int   oi = __shfl_xor(bi, off);
            int   osl = __shfl_xor(bslot, off);
            if (pri_gt(ov, oi, bv, bi)) { bv = ov; bi = oi; bslot = osl; }
        }
        if (lane == 0) { wrs[w] = bv; wri[w] = bi; wrslot[w] = bslot; }
        __syncthreads();
        if (t == 0) {
            float fv = wrs[0]; int fi = wri[0]; int fs = wrslot[0];
            #pragma unroll
            for (int ww = 1; ww < 4; ++ww)
                if (pri_gt(wrs[ww], wri[ww], fv, fi)) {
                    fv = wrs[ww]; fi = wri[ww]; fs = wrslot[ww];
                }
            out[q * KTOP + r]                     = (float)fi;
            out[(size_t)BQ * KTOP + q * KTOP + r] = fv;
            Ls[fs] = NEG_INF; Li[fs] = 0x7fffffff;
        }
        __syncthreads();
    }
}

// ---------------------------------------------------------------------------
extern "C" void kernel_launch(void* const* d_in, const int* in_sizes, int n_in,
                              void* d_out, int out_size, void* d_ws, size_t ws_size,
                              hipStream_t stream)
{
    const float* Qf   = (const float*)d_in[0];
    const float* G    = (const float*)d_in[1];
    const int*   mask = (const int*)d_in[2];
    const int Ntot = in_sizes[1] / DK;                 // 200000

    const int NCH = (Ntot + CHI - 1) / CHI;            // 6250
    int SC = SCN;                                      // 768 sampled chunks
    if (SC > NCH) SC = NCH;

    // ws layout (bytes): ~9.5 MB total
    char* w = (char*)d_ws;
    int*   ocnt = (int*)(w + 0);                       // [0, 1024) control
    int*   gcnt = (int*)(w + 1024);                    // 128 ctrs, 64B apart
    float* thrm = (float*)(w + 10240);                 // 512 B
    unsigned short* Qb = (unsigned short*)(w + 16384); // 48 KB bf16 Q image
    size_t off = 16384 + (size_t)BQ * DK * 2;
    off = (off + 255) & ~(size_t)255;
    float* gmax = (float*)(w + off);                   // SC*128*4
    off += (size_t)SC * BQ * 4; off = (off + 255) & ~(size_t)255;
    float* cs   = (float*)(w + off);                   // 128*CAP*4 = 4 MB
    off += (size_t)BQ * CAP * 4;
    int*   ci   = (int*)(w + off);                     // 4 MB
    off += (size_t)BQ * CAP * 4;
    int*   oqv  = (int*)(w + off);   off += (size_t)OCAP * 4;
    int*   ogv  = (int*)(w + off);   off += (size_t)OCAP * 4;
    float* osv  = (float*)(w + off);

    (void)hipMemsetAsync(w, 0, 16384, stream);
    qprep<<<dim3((BQ * DK + 255) / 256), dim3(256), 0, stream>>>(Qf, Qb);
    score_pass<0><<<dim3(SC), dim3(256), 0, stream>>>(      // sampled maxima
        Qf, Qb, G, mask, thrm, gmax, gcnt, cs, ci, ocnt, oqv, ogv, osv,
        Ntot, NCH, SC);
    thr32<<<dim3(BQ), dim3(256), 0, stream>>>(gmax, thrm, SC);
    score_pass<1><<<dim3(NCH), dim3(256), 0, stream>>>(     // full filter
        Qf, Qb, G, mask, thrm, gmax, gcnt, cs, ci, ocnt, oqv, ogv, osv,
        Ntot, NCH, SC);
    select_topk<<<dim3(BQ), dim3(256), 0, stream>>>(
        cs, ci, gcnt, ocnt, oqv, ogv, osv, (float*)d_out);
}

// Round 16
// 144.177 us; speedup vs baseline: 2.0182x; 1.3602x over previous
//
#include <hip/hip_runtime.h>
#include <hip/hip_bf16.h>
#include <cstdint>
#include <cstddef>

#define BQ 128        // queries (problem-fixed)
#define DK 192        // SIG_DIM
#define KTOP 32
#define CHI 32        // gallery items per chunk (one chunk per block)
#define QCAP 512      // per-block LDS rescore queue
#define CAP 8192      // dense candidate list capacity per query
#define OCAP 65536    // global overflow list
#define MARGIN 0.02f  // > 2x (trunc-G + rne-Q) dot error bound (~0.012)
#define SCN 768       // sampled chunks for threshold
#define THRV 3200     // thr32 LDS value slots

#define NEG_INF (-__builtin_huge_valf())

typedef short short8v __attribute__((ext_vector_type(8)));
typedef float f32x16  __attribute__((ext_vector_type(16)));

__device__ __forceinline__ unsigned fkey(float s) {
    unsigned u = __float_as_uint(s);
    return (u & 0x80000000u) ? ~u : (u | 0x80000000u);   // monotone f32 -> u32
}
__device__ __forceinline__ bool pri_gt(float s1, int i1, float s2, int i2) {
    return (s1 > s2) || (s1 == s2 && i1 < i2);           // jax top_k stability
}
// pack {bf16_trunc(b) : bf16_trunc(a)} in one v_perm_b32 (high halves)
__device__ __forceinline__ unsigned pk_trunc(float a, float b) {
    return __builtin_amdgcn_perm(__float_as_uint(b), __float_as_uint(a),
                                 0x07060302u);
}
__device__ __forceinline__ unsigned f2bf_rne(float x) {
    unsigned u = __float_as_uint(x);
    unsigned r = u + 0x7FFFu + ((u >> 16) & 1u);
    return r >> 16;
}
__device__ __forceinline__ float dot192(const float* __restrict__ a,
                                        const float* __restrict__ b) {
    float s = 0.f;
    #pragma unroll 8
    for (int k = 0; k < DK; ++k) s = fmaf(a[k], b[k], s);
    return s;
}
// async global->LDS DMA, 16B/lane; LDS base wave-uniform (HW adds lane*16)
__device__ __forceinline__ void gload_lds16(const void* g, void* l) {
    __builtin_amdgcn_global_load_lds(
        (const __attribute__((address_space(1))) unsigned int*)g,
        (__attribute__((address_space(3))) unsigned int*)l,
        16, 0, 0);
}

// ---------------------------------------------------------------------------
// qprep: Q fp32 -> bf16 row-major image (RNE) in ws. 24576 elems.
// ---------------------------------------------------------------------------
__global__ __launch_bounds__(256) void qprep(
    const float* __restrict__ Qf, unsigned short* __restrict__ Qb)
{
    const int i = blockIdx.x * 256 + threadIdx.x;
    if (i < BQ * DK) Qb[i] = (unsigned short)f2bf_rne(Qf[i]);
}

// ---------------------------------------------------------------------------
// Straight-line MFMA scoring block: ONE 32-item chunk x all 128 queries.
// G arrives via global_load_lds DMA (coalesced HBM, zero staging VGPRs,
// pre-swizzled source - r14-verified address math). Q fragments hoisted once
// into 48 VGPRs from the bf16 image (L2-hot; overlaps the DMA drain).
// D = mfma(A=Q, B=G): D row = query, D col = item. 12 x {2 ds_read +
// 4 v_perm + MFMA}. LDS ~27 KB -> 5 blocks/CU so co-resident blocks'
// compute covers each block's DMA drain (r14 had only 2 -> serialized).
// MODE 0: masked per-(chunk,q) bf16 max -> gmax[blockIdx][q]   (sampled)
// MODE 1: threshold filter -> LDS queue -> exact fp32 wave-rescore ->
//         dense per-q list via 64B-padded global counters
// __launch_bounds__(256,2): straight-line + loose cap = r9's proven
// no-spill recipe.
// ---------------------------------------------------------------------------
template<int MODE>
__global__ __launch_bounds__(256, 2) void score_pass(
    const float* __restrict__ Qf, const unsigned short* __restrict__ Qb,
    const float* __restrict__ G,
    const int* __restrict__ mask, const float* __restrict__ thrm,
    float* __restrict__ gmax,
    int* __restrict__ gcnt, float* __restrict__ cs, int* __restrict__ ci,
    int* __restrict__ ocnt, int* __restrict__ oq, int* __restrict__ og,
    float* __restrict__ osv,
    int Ntot, int NCH, int SC)
{
    __shared__ float    Gf[CHI * DK];      // 24 KB fp32 G tile (swizzled img)
    __shared__ float    thrmS[BQ];
    __shared__ unsigned queue[QCAP];
    __shared__ int      qn;

    const int t = threadIdx.x;
    const int w = t >> 6, lane = t & 63;
    const int lo5 = lane & 31, hi = lane >> 5;
    const int qbW = w * 32;

    const int chunk = (MODE == 0)
        ? (int)(((long long)blockIdx.x * NCH) / SC)
        : (int)blockIdx.x;
    const int cb = chunk * CHI;

    // ---- G DMA first: 6 instrs, pre-swizzled source (r14-verified)
    #pragma unroll
    for (int i = 0; i < 6; ++i) {
        const int slot = t + (i << 8);
        const int r = slot / 48, c = slot - r * 48;
        size_t grow = (size_t)cb + r;
        if (grow >= (size_t)Ntot) grow = (size_t)Ntot - 1;   // safe dup
        const char* gp = (const char*)G + grow * (DK * 4) + ((c ^ (r & 7)) << 4);
        char* lp = (char*)Gf + ((i << 2) + w) * 1024;        // wave-uniform
        gload_lds16(gp, lp);
    }

    // ---- hoist Q fragments (bf16 image, L2-hot; overlaps the DMA drain)
    uint4 aF[12];
    {
        const unsigned short* qp = Qb + (size_t)(qbW + lo5) * DK + hi * 8;
        #pragma unroll
        for (int s = 0; s < 12; ++s)
            aF[s] = *reinterpret_cast<const uint4*>(qp + s * 16);
    }

    if (t < BQ) thrmS[t] = (MODE == 1) ? thrm[t] : 0.f;
    if (t == 0) qn = 0;
    __syncthreads();                 // drains DMA (vmcnt before s_barrier)

    const unsigned xsh = (unsigned)((lo5 & 7) << 4);
    const char* rowp = (const char*)Gf + lo5 * (DK * 4);

    f32x16 acc = {0,0,0,0,0,0,0,0,0,0,0,0,0,0,0,0};
    #pragma unroll
    for (int s = 0; s < 12; ++s) {
        const unsigned b0 = ((unsigned)((s * 4 + hi * 2) << 4)) ^ xsh;
        const unsigned b1 = ((unsigned)((s * 4 + hi * 2 + 1) << 4)) ^ xsh;
        float4 f0 = *reinterpret_cast<const float4*>(rowp + b0);
        float4 f1 = *reinterpret_cast<const float4*>(rowp + b1);
        union { unsigned u[4]; short8v v; } bu;
        bu.u[0] = pk_trunc(f0.x, f0.y); bu.u[1] = pk_trunc(f0.z, f0.w);
        bu.u[2] = pk_trunc(f1.x, f1.y); bu.u[3] = pk_trunc(f1.z, f1.w);
        union { uint4 u; short8v v; } au; au.u = aF[s];
        acc = __builtin_amdgcn_mfma_f32_32x32x16_bf16(au.v, bu.v, acc, 0, 0, 0);
    }

    // D layout: row(query) = (j&3)+8*(j>>2)+4*hi (+qbW), col(item) = lane&31
    const int g = cb + lo5;
    if (MODE == 0) {
        #pragma unroll
        for (int j = 0; j < 16; ++j) {
            const int row = (j & 3) + 8 * (j >> 2) + 4 * hi;
            const int q = qbW + row;
            float m = NEG_INF;
            if (g < Ntot && !mask[(size_t)q * (size_t)Ntot + g])
                m = acc[j];
            #pragma unroll
            for (int off = 1; off < 32; off <<= 1)        // within 32-lane half
                m = fmaxf(m, __shfl_xor(m, off));
            if (lo5 == 0) gmax[(size_t)blockIdx.x * BQ + q] = m;
        }
    } else {
        #pragma unroll
        for (int j = 0; j < 16; ++j) {
            const int row = (j & 3) + 8 * (j >> 2) + 4 * hi;
            const int q = qbW + row;
            const float th = thrmS[q];
            const float s = acc[j];
            if (g < Ntot && s >= th) {
                if (!mask[(size_t)q * (size_t)Ntot + g]) {   // coalesced per j
                    const int p = atomicAdd(&qn, 1);
                    if (p < QCAP) {
                        queue[p] = ((unsigned)q << 24) | (unsigned)g;
                    } else {   // pathological: inline exact rescore
                        float sx = dot192(Qf + q * DK, G + (size_t)g * DK);
                        const int op = atomicAdd(ocnt, 1);
                        if (op < OCAP) { oq[op] = q; og[op] = g; osv[op] = sx; }
                    }
                }
            }
        }
        __syncthreads();
        const int nq = qn < QCAP ? qn : QCAP;
        for (int cc = w; cc < nq; cc += 4) {       // one wave per candidate
            const unsigned pk = queue[cc];
            const int q = pk >> 24, gg = pk & 0xFFFFFF;
            const float* qr = Qf + q * DK;
            const float* gr = G + (size_t)gg * DK;
            const int k0 = lane * 3;
            float part = qr[k0] * gr[k0];
            part = fmaf(qr[k0 + 1], gr[k0 + 1], part);
            part = fmaf(qr[k0 + 2], gr[k0 + 2], part);
            #pragma unroll
            for (int off = 32; off > 0; off >>= 1)
                part += __shfl_xor(part, off);
            if (lane == 0) {
                const int pos = atomicAdd(&gcnt[q * 16], 1);   // 64B-padded
                if (pos < CAP) {
                    cs[(size_t)q * CAP + pos] = part;
                    ci[(size_t)q * CAP + pos] = gg;
                } else {
                    const int op = atomicAdd(ocnt, 1);
                    if (op < OCAP) { oq[op] = q; og[op] = gg; osv[op] = part; }
                }
            }
        }
    }
}

// ---------------------------------------------------------------------------
// thrm[q] = (exact 32nd-largest of SC sampled masked chunk-maxima) - MARGIN.
// Valid bound: 32 distinct unmasked witnesses with bf16 score >= thr.
// ---------------------------------------------------------------------------
__global__ __launch_bounds__(256) void thr32(
    const float* __restrict__ gmax, float* __restrict__ thrm, int SC)
{
    __shared__ float vals[THRV];
    __shared__ int hist[256];
    __shared__ int hscan[256];
    __shared__ int bS, gtS;

    const int q = blockIdx.x;
    const int t = threadIdx.x;
    const int M = SC < THRV ? SC : THRV;

    for (int i = t; i < M; i += 256) {
        float m = gmax[(size_t)i * BQ + q];
        for (int j = i + THRV; j < SC; j += THRV)
            m = fmaxf(m, gmax[(size_t)j * BQ + q]);
        vals[i] = m;
    }
    __syncthreads();

    unsigned prefix = 0, pmask = 0;
    int kneed = KTOP;
    for (int pass = 0; pass < 4; ++pass) {
        const int shift = 24 - pass * 8;
        hist[t] = 0;
        __syncthreads();
        for (int i = t; i < M; i += 256) {
            unsigned k = fkey(vals[i]);
            if ((k & pmask) == prefix) atomicAdd(&hist[(k >> shift) & 255], 1);
        }
        __syncthreads();
        int* src = hist; int* dst = hscan;
        for (int off = 1; off < 256; off <<= 1) {
            int v = src[t] + ((t + off) < 256 ? src[t + off] : 0);
            __syncthreads();
            dst[t] = v;
            __syncthreads();
            int* tmp = src; src = dst; dst = tmp;
        }
        if (src[t] >= kneed && (t == 255 || src[t + 1] < kneed)) {
            bS = t; gtS = (t == 255) ? 0 : src[t + 1];
        }
        __syncthreads();
        kneed -= gtS;
        prefix |= ((unsigned)bS) << shift;
        pmask  |= 0xFFu << shift;
        __syncthreads();
    }
    if (t == 0) {
        unsigned u = (prefix & 0x80000000u) ? (prefix & 0x7FFFFFFFu) : ~prefix;
        thrm[q] = __uint_as_float(u) - MARGIN;
    }
}

// ---------------------------------------------------------------------------
// Exact per-query top-32 over dense candidate list (+overflow): 4-pass radix
// select + collect + tie-breaking tournament (score desc, idx asc).
// out: [0..B*K) = indices (as float); [B*K..2BK) = scores.
// ---------------------------------------------------------------------------
__global__ __launch_bounds__(256) void select_topk(
    const float* __restrict__ cs, const int* __restrict__ ci,
    const int* __restrict__ gcnt,
    const int* __restrict__ ocnt, const int* __restrict__ oq,
    const int* __restrict__ og, const float* __restrict__ osv,
    float* __restrict__ out)
{
    __shared__ int   hist[256];
    __shared__ int   hscan[256];
    __shared__ float Ls[256];
    __shared__ int   Li[256];
    __shared__ int   lcnt, nTotS, bS, gtS;
    __shared__ float wrs[4]; __shared__ int wri[4], wrslot[4];

    const int q = blockIdx.x;
    const int t = threadIdx.x;
    const int n0 = gcnt[q * 16];
    const int n = n0 < CAP ? n0 : CAP;
    const size_t base = (size_t)q * CAP;
    const int novf0 = *ocnt;
    const int novf = novf0 < OCAP ? novf0 : OCAP;

    if (t == 0) nTotS = 0;
    __syncthreads();
    {
        int part = (t == 0) ? n : 0;
        for (int i = t; i < novf; i += 256)
            if (oq[i] == q) part++;
        atomicAdd(&nTotS, part);
    }
    __syncthreads();
    const int nTot = nTotS;

    unsigned prefix = 0, pmask = 0;
    int kneed = KTOP;

    if (nTot > KTOP) {
        for (int pass = 0; pass < 4; ++pass) {
            const int shift = 24 - pass * 8;
            hist[t] = 0;
            __syncthreads();
            for (int i = t; i < n; i += 256) {
                unsigned k = fkey(cs[base + i]);
                if ((k & pmask) == prefix)
                    atomicAdd(&hist[(k >> shift) & 255], 1);
            }
            for (int i = t; i < novf; i += 256) {
                if (oq[i] == q) {
                    unsigned k = fkey(osv[i]);
                    if ((k & pmask) == prefix)
                        atomicAdd(&hist[(k >> shift) & 255], 1);
                }
            }
            __syncthreads();
            int* src = hist; int* dst = hscan;
            for (int off = 1; off < 256; off <<= 1) {
                int v = src[t] + ((t + off) < 256 ? src[t + off] : 0);
                __syncthreads();
                dst[t] = v;
                __syncthreads();
                int* tmp = src; src = dst; dst = tmp;
            }
            if (src[t] >= kneed && (t == 255 || src[t + 1] < kneed)) {
                bS = t;
                gtS = (t == 255) ? 0 : src[t + 1];
            }
            __syncthreads();
            const int b = bS;
            kneed -= gtS;
            prefix |= ((unsigned)b) << shift;
            pmask  |= 0xFFu << shift;
            __syncthreads();
        }
    }

    if (t == 0) lcnt = 0;
    __syncthreads();
    const unsigned T = (nTot > KTOP) ? prefix : 0u;
    for (int i = t; i < n; i += 256) {
        float s = cs[base + i];
        if (fkey(s) >= T) {
            int p = atomicAdd(&lcnt, 1);
            if (p < 256) { Ls[p] = s; Li[p] = ci[base + i]; }
        }
    }
    for (int i = t; i < novf; i += 256) {
        if (oq[i] == q) {
            float s = osv[i];
            if (fkey(s) >= T) {
                int p = atomicAdd(&lcnt, 1);
                if (p < 256) { Ls[p] = s; Li[p] = og[i]; }
            }
        }
    }
    __syncthreads();
    const int M = lcnt < 256 ? lcnt : 256;

    const int w = t >> 6, lane = t & 63;
    for (int r = 0; r < KTOP; ++r) {
        float bv = (t < M) ? Ls[t] : NEG_INF;
        int   bi = (t < M) ? Li[t] : 0x7fffffff;
        int   bslot = t;
        #pragma unroll
        for (int off = 32; off > 0; off >>= 1) {
            float ov = __shfl_xor(bv, off);
            int   oi = __shfl_xor(bi, off);
            int   osl = __shfl_xor(bslot, off);
            if (pri_gt(ov, oi, bv, bi)) { bv = ov; bi = oi; bslot = osl; }
        }
        if (lane == 0) { wrs[w] = bv; wri[w] = bi; wrslot[w] = bslot; }
        __syncthreads();
        if (t == 0) {
            float fv = wrs[0]; int fi = wri[0]; int fs = wrslot[0];
            #pragma unroll
            for (int ww = 1; ww < 4; ++ww)
                if (pri_gt(wrs[ww], wri[ww], fv, fi)) {
                    fv = wrs[ww]; fi = wri[ww]; fs = wrslot[ww];
                }
            out[q * KTOP + r]                     = (float)fi;
            out[(size_t)BQ * KTOP + q * KTOP + r] = fv;
            Ls[fs] = NEG_INF; Li[fs] = 0x7fffffff;
        }
        __syncthreads();
    }
}

// ---------------------------------------------------------------------------
extern "C" void kernel_launch(void* const* d_in, const int* in_sizes, int n_in,
                              void* d_out, int out_size, void* d_ws, size_t ws_size,
                              hipStream_t stream)
{
    const float* Qf   = (const float*)d_in[0];
    const float* G    = (const float*)d_in[1];
    const int*   mask = (const int*)d_in[2];
    const int Ntot = in_sizes[1] / DK;                 // 200000

    const int NCH = (Ntot + CHI - 1) / CHI;            // 6250
    int SC = SCN;                                      // 768 sampled chunks
    if (SC > NCH) SC = NCH;

    // ws layout (bytes): ~9.5 MB total
    char* w = (char*)d_ws;
    int*   ocnt = (int*)(w + 0);                       // [0, 1024) control
    int*   gcnt = (int*)(w + 1024);                    // 128 ctrs, 64B apart
    float* thrm = (float*)(w + 10240);                 // 512 B
    unsigned short* Qb = (unsigned short*)(w + 16384); // 48 KB bf16 Q image
    size_t off = 16384 + (size_t)BQ * DK * 2;
    off = (off + 255) & ~(size_t)255;
    float* gmax = (float*)(w + off);                   // SC*128*4
    off += (size_t)SC * BQ * 4; off = (off + 255) & ~(size_t)255;
    float* cs   = (float*)(w + off);                   // 128*CAP*4 = 4 MB
    off += (size_t)BQ * CAP * 4;
    int*   ci   = (int*)(w + off);                     // 4 MB
    off += (size_t)BQ * CAP * 4;
    int*   oqv  = (int*)(w + off);   off += (size_t)OCAP * 4;
    int*   ogv  = (int*)(w + off);   off += (size_t)OCAP * 4;
    float* osv  = (float*)(w + off);

    (void)hipMemsetAsync(w, 0, 16384, stream);
    qprep<<<dim3((BQ * DK + 255) / 256), dim3(256), 0, stream>>>(Qf, Qb);
    score_pass<0><<<dim3(SC), dim3(256), 0, stream>>>(      // sampled maxima
        Qf, Qb, G, mask, thrm, gmax, gcnt, cs, ci, ocnt, oqv, ogv, osv,
        Ntot, NCH, SC);
    thr32<<<dim3(BQ), dim3(256), 0, stream>>>(gmax, thrm, SC);
    score_pass<1><<<dim3(NCH), dim3(256), 0, stream>>>(     // full filter
        Qf, Qb, G, mask, thrm, gmax, gcnt, cs, ci, ocnt, oqv, ogv, osv,
        Ntot, NCH, SC);
    select_topk<<<dim3(BQ), dim3(256), 0, stream>>>(
        cs, ci, gcnt, ocnt, oqv, ogv, osv, (float*)d_out);
}

// Round 17
// 139.533 us; speedup vs baseline: 2.0854x; 1.0333x over previous
//
#include <hip/hip_runtime.h>
#include <hip/hip_bf16.h>
#include <cstdint>
#include <cstddef>

#define BQ 128        // queries (problem-fixed)
#define DK 192        // SIG_DIM
#define KTOP 32
#define CHI 64        // gallery items per chunk (2 MFMA tiles per block)
#define QCAP 512      // per-block LDS rescore queue
#define CAP 8192      // dense candidate list capacity per query
#define OCAP 65536    // global overflow list
#define MARGIN 0.02f  // > 2x (trunc-G + rne-Q) dot error bound (~0.012)
#define SCN 768       // sampled chunks for threshold
#define THRV 3200     // thr32 LDS value slots

#define NEG_INF (-__builtin_huge_valf())

typedef short short8v __attribute__((ext_vector_type(8)));
typedef float f32x16  __attribute__((ext_vector_type(16)));

__device__ __forceinline__ unsigned fkey(float s) {
    unsigned u = __float_as_uint(s);
    return (u & 0x80000000u) ? ~u : (u | 0x80000000u);   // monotone f32 -> u32
}
__device__ __forceinline__ bool pri_gt(float s1, int i1, float s2, int i2) {
    return (s1 > s2) || (s1 == s2 && i1 < i2);           // jax top_k stability
}
// pack {bf16_trunc(b) : bf16_trunc(a)} in one v_perm_b32 (high halves)
__device__ __forceinline__ unsigned pk_trunc(float a, float b) {
    return __builtin_amdgcn_perm(__float_as_uint(b), __float_as_uint(a),
                                 0x07060302u);
}
__device__ __forceinline__ unsigned f2bf_rne(float x) {
    unsigned u = __float_as_uint(x);
    unsigned r = u + 0x7FFFu + ((u >> 16) & 1u);
    return r >> 16;
}
__device__ __forceinline__ float dot192(const float* __restrict__ a,
                                        const float* __restrict__ b) {
    float s = 0.f;
    #pragma unroll 8
    for (int k = 0; k < DK; ++k) s = fmaf(a[k], b[k], s);
    return s;
}
// async global->LDS DMA, 16B/lane; LDS base wave-uniform (HW adds lane*16)
__device__ __forceinline__ void gload_lds16(const void* g, void* l) {
    __builtin_amdgcn_global_load_lds(
        (const __attribute__((address_space(1))) unsigned int*)g,
        (__attribute__((address_space(3))) unsigned int*)l,
        16, 0, 0);
}

// ---------------------------------------------------------------------------
// qprep: Q fp32 -> bf16 row-major image (RNE) in ws. 24576 elems.
// ---------------------------------------------------------------------------
__global__ __launch_bounds__(256) void qprep(
    const float* __restrict__ Qf, unsigned short* __restrict__ Qb)
{
    const int i = blockIdx.x * 256 + threadIdx.x;
    if (i < BQ * DK) Qb[i] = (unsigned short)f2bf_rne(Qf[i]);
}

// ---------------------------------------------------------------------------
// Straight-line MFMA scoring block: ONE 64-item chunk x all 128 queries.
// G arrives via global_load_lds DMA (12 instrs, pre-swizzled source).
// Q fragments hoisted into 48 VGPRs and PINNED with an asm barrier so the
// compiler cannot sink/rematerialize the loads into the MFMA loop (the
// r16 latency killer: VGPR=40 meant 12 in-loop L2 loads on the dep chain).
// D = mfma(A=Q, B=G): 2 item-tiles, 12 x {4 ds_read + 8 v_perm + 2 MFMA}.
// LDS ~51 KB -> 3 blocks/CU.
// MODE 0: masked per-(chunk,q) bf16 max -> gmax[blockIdx][q]   (sampled)
// MODE 1: threshold filter -> LDS queue -> exact fp32 wave-rescore ->
//         dense per-q list via 64B-padded global counters
// ---------------------------------------------------------------------------
template<int MODE>
__global__ __launch_bounds__(256, 2) void score_pass(
    const float* __restrict__ Qf, const unsigned short* __restrict__ Qb,
    const float* __restrict__ G,
    const int* __restrict__ mask, const float* __restrict__ thrm,
    float* __restrict__ gmax,
    int* __restrict__ gcnt, float* __restrict__ cs, int* __restrict__ ci,
    int* __restrict__ ocnt, int* __restrict__ oq, int* __restrict__ og,
    float* __restrict__ osv,
    int Ntot, int NCH, int SC)
{
    __shared__ float    Gf[CHI * DK];      // 48 KB fp32 G tile (swizzled img)
    __shared__ float    thrmS[BQ];
    __shared__ unsigned queue[QCAP];
    __shared__ int      qn;

    const int t = threadIdx.x;
    const int w = t >> 6, lane = t & 63;
    const int lo5 = lane & 31, hi = lane >> 5;
    const int qbW = w * 32;

    const int chunk = (MODE == 0)
        ? (int)(((long long)blockIdx.x * NCH) / SC)
        : (int)blockIdx.x;
    const int cb = chunk * CHI;

    // ---- G DMA first: 12 instrs, pre-swizzled source (r14/r16-verified math)
    #pragma unroll
    for (int i = 0; i < 12; ++i) {
        const int slot = t + (i << 8);
        const int r = slot / 48, c = slot - r * 48;
        size_t grow = (size_t)cb + r;
        if (grow >= (size_t)Ntot) grow = (size_t)Ntot - 1;   // safe dup
        const char* gp = (const char*)G + grow * (DK * 4) + ((c ^ (r & 7)) << 4);
        char* lp = (char*)Gf + ((i << 2) + w) * 1024;        // wave-uniform
        gload_lds16(gp, lp);
    }

    // ---- hoist Q fragments (bf16 image, L2-hot; overlaps DMA drain), PINNED
    uint4 aF[12];
    {
        const unsigned short* qp = Qb + (size_t)(qbW + lo5) * DK + hi * 8;
        #pragma unroll
        for (int s = 0; s < 12; ++s)
            aF[s] = *reinterpret_cast<const uint4*>(qp + s * 16);
    }
    #pragma unroll
    for (int s = 0; s < 12; ++s)
        asm volatile("" : "+v"(aF[s].x), "+v"(aF[s].y),
                          "+v"(aF[s].z), "+v"(aF[s].w));   // forbid sinking

    if (t < BQ) thrmS[t] = (MODE == 1) ? thrm[t] : 0.f;
    if (t == 0) qn = 0;
    __syncthreads();                 // drains DMA (vmcnt before s_barrier)

    const unsigned xsh = (unsigned)((lo5 & 7) << 4);
    const char* rowp0 = (const char*)Gf + lo5 * (DK * 4);          // tile 0
    const char* rowp1 = (const char*)Gf + (32 + lo5) * (DK * 4);   // tile 1

    f32x16 acc[2] = {
        {0,0,0,0,0,0,0,0,0,0,0,0,0,0,0,0}, {0,0,0,0,0,0,0,0,0,0,0,0,0,0,0,0}};
    #pragma unroll
    for (int s = 0; s < 12; ++s) {
        const unsigned b0 = ((unsigned)((s * 4 + hi * 2) << 4)) ^ xsh;
        const unsigned b1 = ((unsigned)((s * 4 + hi * 2 + 1) << 4)) ^ xsh;
        union { uint4 u; short8v v; } au; au.u = aF[s];
        {
            float4 f0 = *reinterpret_cast<const float4*>(rowp0 + b0);
            float4 f1 = *reinterpret_cast<const float4*>(rowp0 + b1);
            union { unsigned u[4]; short8v v; } bu;
            bu.u[0] = pk_trunc(f0.x, f0.y); bu.u[1] = pk_trunc(f0.z, f0.w);
            bu.u[2] = pk_trunc(f1.x, f1.y); bu.u[3] = pk_trunc(f1.z, f1.w);
            acc[0] = __builtin_amdgcn_mfma_f32_32x32x16_bf16(au.v, bu.v, acc[0], 0, 0, 0);
        }
        {
            float4 f0 = *reinterpret_cast<const float4*>(rowp1 + b0);
            float4 f1 = *reinterpret_cast<const float4*>(rowp1 + b1);
            union { unsigned u[4]; short8v v; } bu;
            bu.u[0] = pk_trunc(f0.x, f0.y); bu.u[1] = pk_trunc(f0.z, f0.w);
            bu.u[2] = pk_trunc(f1.x, f1.y); bu.u[3] = pk_trunc(f1.z, f1.w);
            acc[1] = __builtin_amdgcn_mfma_f32_32x32x16_bf16(au.v, bu.v, acc[1], 0, 0, 0);
        }
    }

    // D layout: row(query) = (j&3)+8*(j>>2)+4*hi (+qbW), col(item) = lane&31
    if (MODE == 0) {
        #pragma unroll
        for (int j = 0; j < 16; ++j) {
            const int row = (j & 3) + 8 * (j >> 2) + 4 * hi;
            const int q = qbW + row;
            const size_t mrow = (size_t)q * (size_t)Ntot;
            float m = NEG_INF;
            #pragma unroll
            for (int st = 0; st < 2; ++st) {
                const int g = cb + st * 32 + lo5;
                if (g < Ntot && !mask[mrow + g]) m = fmaxf(m, acc[st][j]);
            }
            #pragma unroll
            for (int off = 1; off < 32; off <<= 1)        // within 32-lane half
                m = fmaxf(m, __shfl_xor(m, off));
            if (lo5 == 0) gmax[(size_t)blockIdx.x * BQ + q] = m;
        }
    } else {
        #pragma unroll
        for (int j = 0; j < 16; ++j) {
            const int row = (j & 3) + 8 * (j >> 2) + 4 * hi;
            const int q = qbW + row;
            const float th = thrmS[q];
            #pragma unroll
            for (int st = 0; st < 2; ++st) {
                const int g = cb + st * 32 + lo5;
                const float s = acc[st][j];
                if (g < Ntot && s >= th) {
                    if (!mask[(size_t)q * (size_t)Ntot + g]) {   // coalesced
                        const int p = atomicAdd(&qn, 1);
                        if (p < QCAP) {
                            queue[p] = ((unsigned)q << 24) | (unsigned)g;
                        } else {   // pathological: inline exact rescore
                            float sx = dot192(Qf + q * DK, G + (size_t)g * DK);
                            const int op = atomicAdd(ocnt, 1);
                            if (op < OCAP) { oq[op] = q; og[op] = g; osv[op] = sx; }
                        }
                    }
                }
            }
        }
        __syncthreads();
        const int nq = qn < QCAP ? qn : QCAP;
        for (int cc = w; cc < nq; cc += 4) {       // one wave per candidate
            const unsigned pk = queue[cc];
            const int q = pk >> 24, gg = pk & 0xFFFFFF;
            const float* qr = Qf + q * DK;
            const float* gr = G + (size_t)gg * DK;
            const int k0 = lane * 3;
            float part = qr[k0] * gr[k0];
            part = fmaf(qr[k0 + 1], gr[k0 + 1], part);
            part = fmaf(qr[k0 + 2], gr[k0 + 2], part);
            #pragma unroll
            for (int off = 32; off > 0; off >>= 1)
                part += __shfl_xor(part, off);
            if (lane == 0) {
                const int pos = atomicAdd(&gcnt[q * 16], 1);   // 64B-padded
                if (pos < CAP) {
                    cs[(size_t)q * CAP + pos] = part;
                    ci[(size_t)q * CAP + pos] = gg;
                } else {
                    const int op = atomicAdd(ocnt, 1);
                    if (op < OCAP) { oq[op] = q; og[op] = gg; osv[op] = part; }
                }
            }
        }
    }
}

// ---------------------------------------------------------------------------
// thrm[q] = (exact 32nd-largest of SC sampled masked chunk-maxima) - MARGIN.
// Valid bound: 32 distinct unmasked witnesses with bf16 score >= thr.
// ---------------------------------------------------------------------------
__global__ __launch_bounds__(256) void thr32(
    const float* __restrict__ gmax, float* __restrict__ thrm, int SC)
{
    __shared__ float vals[THRV];
    __shared__ int hist[256];
    __shared__ int hscan[256];
    __shared__ int bS, gtS;

    const int q = blockIdx.x;
    const int t = threadIdx.x;
    const int M = SC < THRV ? SC : THRV;

    for (int i = t; i < M; i += 256) {
        float m = gmax[(size_t)i * BQ + q];
        for (int j = i + THRV; j < SC; j += THRV)
            m = fmaxf(m, gmax[(size_t)j * BQ + q]);
        vals[i] = m;
    }
    __syncthreads();

    unsigned prefix = 0, pmask = 0;
    int kneed = KTOP;
    for (int pass = 0; pass < 4; ++pass) {
        const int shift = 24 - pass * 8;
        hist[t] = 0;
        __syncthreads();
        for (int i = t; i < M; i += 256) {
            unsigned k = fkey(vals[i]);
            if ((k & pmask) == prefix) atomicAdd(&hist[(k >> shift) & 255], 1);
        }
        __syncthreads();
        int* src = hist; int* dst = hscan;
        for (int off = 1; off < 256; off <<= 1) {
            int v = src[t] + ((t + off) < 256 ? src[t + off] : 0);
            __syncthreads();
            dst[t] = v;
            __syncthreads();
            int* tmp = src; src = dst; dst = tmp;
        }
        if (src[t] >= kneed && (t == 255 || src[t + 1] < kneed)) {
            bS = t; gtS = (t == 255) ? 0 : src[t + 1];
        }
        __syncthreads();
        kneed -= gtS;
        prefix |= ((unsigned)bS) << shift;
        pmask  |= 0xFFu << shift;
        __syncthreads();
    }
    if (t == 0) {
        unsigned u = (prefix & 0x80000000u) ? (prefix & 0x7FFFFFFFu) : ~prefix;
        thrm[q] = __uint_as_float(u) - MARGIN;
    }
}

// ---------------------------------------------------------------------------
// Exact per-query top-32 over dense candidate list (+overflow): 4-pass radix
// select + collect + tie-breaking tournament (score desc, idx asc).
// out: [0..B*K) = indices (as float); [B*K..2BK) = scores.
// ---------------------------------------------------------------------------
__global__ __launch_bounds__(256) void select_topk(
    const float* __restrict__ cs, const int* __restrict__ ci,
    const int* __restrict__ gcnt,
    const int* __restrict__ ocnt, const int* __restrict__ oq,
    const int* __restrict__ og, const float* __restrict__ osv,
    float* __restrict__ out)
{
    __shared__ int   hist[256];
    __shared__ int   hscan[256];
    __shared__ float Ls[256];
    __shared__ int   Li[256];
    __shared__ int   lcnt, nTotS, bS, gtS;
    __shared__ float wrs[4]; __shared__ int wri[4], wrslot[4];

    const int q = blockIdx.x;
    const int t = threadIdx.x;
    const int n0 = gcnt[q * 16];
    const int n = n0 < CAP ? n0 : CAP;
    const size_t base = (size_t)q * CAP;
    const int novf0 = *ocnt;
    const int novf = novf0 < OCAP ? novf0 : OCAP;

    if (t == 0) nTotS = 0;
    __syncthreads();
    {
        int part = (t == 0) ? n : 0;
        for (int i = t; i < novf; i += 256)
            if (oq[i] == q) part++;
        atomicAdd(&nTotS, part);
    }
    __syncthreads();
    const int nTot = nTotS;

    unsigned prefix = 0, pmask = 0;
    int kneed = KTOP;

    if (nTot > KTOP) {
        for (int pass = 0; pass < 4; ++pass) {
            const int shift = 24 - pass * 8;
            hist[t] = 0;
            __syncthreads();
            for (int i = t; i < n; i += 256) {
                unsigned k = fkey(cs[base + i]);
                if ((k & pmask) == prefix)
                    atomicAdd(&hist[(k >> shift) & 255], 1);
            }
            for (int i = t; i < novf; i += 256) {
                if (oq[i] == q) {
                    unsigned k = fkey(osv[i]);
                    if ((k & pmask) == prefix)
                        atomicAdd(&hist[(k >> shift) & 255], 1);
                }
            }
            __syncthreads();
            int* src = hist; int* dst = hscan;
            for (int off = 1; off < 256; off <<= 1) {
                int v = src[t] + ((t + off) < 256 ? src[t + off] : 0);
                __syncthreads();
                dst[t] = v;
                __syncthreads();
                int* tmp = src; src = dst; dst = tmp;
            }
            if (src[t] >= kneed && (t == 255 || src[t + 1] < kneed)) {
                bS = t;
                gtS = (t == 255) ? 0 : src[t + 1];
            }
            __syncthreads();
            const int b = bS;
            kneed -= gtS;
            prefix |= ((unsigned)b) << shift;
            pmask  |= 0xFFu << shift;
            __syncthreads();
        }
    }

    if (t == 0) lcnt = 0;
    __syncthreads();
    const unsigned T = (nTot > KTOP) ? prefix : 0u;
    for (int i = t; i < n; i += 256) {
        float s = cs[base + i];
        if (fkey(s) >= T) {
            int p = atomicAdd(&lcnt, 1);
            if (p < 256) { Ls[p] = s; Li[p] = ci[base + i]; }
        }
    }
    for (int i = t; i < novf; i += 256) {
        if (oq[i] == q) {
            float s = osv[i];
            if (fkey(s) >= T) {
                int p = atomicAdd(&lcnt, 1);
                if (p < 256) { Ls[p] = s; Li[p] = og[i]; }
            }
        }
    }
    __syncthreads();
    const int M = lcnt < 256 ? lcnt : 256;

    const int w = t >> 6, lane = t & 63;
    for (int r = 0; r < KTOP; ++r) {
        float bv = (t < M) ? Ls[t] : NEG_INF;
        int   bi = (t < M) ? Li[t] : 0x7fffffff;
        int   bslot = t;
        #pragma unroll
        for (int off = 32; off > 0; off >>= 1) {
            float ov = __shfl_xor(bv, off);
            int   oi = __shfl_xor(bi, off);
            int   osl = __shfl_xor(bslot, off);
            if (pri_gt(ov, oi, bv, bi)) { bv = ov; bi = oi; bslot = osl; }
        }
        if (lane == 0) { wrs[w] = bv; wri[w] = bi; wrslot[w] = bslot; }
        __syncthreads();
        if (t == 0) {
            float fv = wrs[0]; int fi = wri[0]; int fs = wrslot[0];
            #pragma unroll
            for (int ww = 1; ww < 4; ++ww)
                if (pri_gt(wrs[ww], wri[ww], fv, fi)) {
                    fv = wrs[ww]; fi = wri[ww]; fs = wrslot[ww];
                }
            out[q * KTOP + r]                     = (float)fi;
            out[(size_t)BQ * KTOP + q * KTOP + r] = fv;
            Ls[fs] = NEG_INF; Li[fs] = 0x7fffffff;
        }
        __syncthreads();
    }
}

// ---------------------------------------------------------------------------
extern "C" void kernel_launch(void* const* d_in, const int* in_sizes, int n_in,
                              void* d_out, int out_size, void* d_ws, size_t ws_size,
                              hipStream_t stream)
{
    const float* Qf   = (const float*)d_in[0];
    const float* G    = (const float*)d_in[1];
    const int*   mask = (const int*)d_in[2];
    const int Ntot = in_sizes[1] / DK;                 // 200000

    const int NCH = (Ntot + CHI - 1) / CHI;            // 3125
    int SC = SCN;                                      // 768 sampled chunks
    if (SC > NCH) SC = NCH;

    // ws layout (bytes): ~9.5 MB total
    char* w = (char*)d_ws;
    int*   ocnt = (int*)(w + 0);                       // [0, 1024) control
    int*   gcnt = (int*)(w + 1024);                    // 128 ctrs, 64B apart
    float* thrm = (float*)(w + 10240);                 // 512 B
    unsigned short* Qb = (unsigned short*)(w + 16384); // 48 KB bf16 Q image
    size_t off = 16384 + (size_t)BQ * DK * 2;
    off = (off + 255) & ~(size_t)255;
    float* gmax = (float*)(w + off);                   // SC*128*4
    off += (size_t)SC * BQ * 4; off = (off + 255) & ~(size_t)255;
    float* cs   = (float*)(w + off);                   // 128*CAP*4 = 4 MB
    off += (size_t)BQ * CAP * 4;
    int*   ci   = (int*)(w + off);                     // 4 MB
    off += (size_t)BQ * CAP * 4;
    int*   oqv  = (int*)(w + off);   off += (size_t)OCAP * 4;
    int*   ogv  = (int*)(w + off);   off += (size_t)OCAP * 4;
    float* osv  = (float*)(w + off);

    (void)hipMemsetAsync(w, 0, 16384, stream);
    qprep<<<dim3((BQ * DK + 255) / 256), dim3(256), 0, stream>>>(Qf, Qb);
    score_pass<0><<<dim3(SC), dim3(256), 0, stream>>>(      // sampled maxima
        Qf, Qb, G, mask, thrm, gmax, gcnt, cs, ci, ocnt, oqv, ogv, osv,
        Ntot, NCH, SC);
    thr32<<<dim3(BQ), dim3(256), 0, stream>>>(gmax, thrm, SC);
    score_pass<1><<<dim3(NCH), dim3(256), 0, stream>>>(     // full filter
        Qf, Qb, G, mask, thrm, gmax, gcnt, cs, ci, ocnt, oqv, ogv, osv,
        Ntot, NCH, SC);
    select_topk<<<dim3(BQ), dim3(256), 0, stream>>>(
        cs, ci, gcnt, ocnt, oqv, ogv, osv, (float*)d_out);
}

// Round 18
// 130.503 us; speedup vs baseline: 2.2296x; 1.0692x over previous
//
#include <hip/hip_runtime.h>
#include <hip/hip_bf16.h>
#include <cstdint>
#include <cstddef>

#define BQ 128        // queries (problem-fixed)
#define DK 192        // SIG_DIM
#define KTOP 32
#define CHI 64        // gallery items per chunk (2 MFMA tiles per block)
#define QCAP 512      // per-block LDS rescore queue
#define CAP 8192      // dense candidate list capacity per query
#define OCAP 65536    // global overflow list
#define MARGIN 0.02f  // > 2x (trunc-G + rne-Q) dot error bound (~0.012)
#define SCN 768       // sampled chunks for threshold
#define THRV 3200     // thr32 LDS value slots

#define NEG_INF (-__builtin_huge_valf())

typedef short short8v __attribute__((ext_vector_type(8)));
typedef float f32x16  __attribute__((ext_vector_type(16)));

__device__ __forceinline__ unsigned fkey(float s) {
    unsigned u = __float_as_uint(s);
    return (u & 0x80000000u) ? ~u : (u | 0x80000000u);   // monotone f32 -> u32
}
__device__ __forceinline__ bool pri_gt(float s1, int i1, float s2, int i2) {
    return (s1 > s2) || (s1 == s2 && i1 < i2);           // jax top_k stability
}
// pack {bf16_trunc(b) : bf16_trunc(a)} in one v_perm_b32 (high halves)
__device__ __forceinline__ unsigned pk_trunc(float a, float b) {
    return __builtin_amdgcn_perm(__float_as_uint(b), __float_as_uint(a),
                                 0x07060302u);
}
__device__ __forceinline__ unsigned f2bf_rne(float x) {
    unsigned u = __float_as_uint(x);
    unsigned r = u + 0x7FFFu + ((u >> 16) & 1u);
    return r >> 16;
}
__device__ __forceinline__ float dot192(const float* __restrict__ a,
                                        const float* __restrict__ b) {
    float s = 0.f;
    #pragma unroll 8
    for (int k = 0; k < DK; ++k) s = fmaf(a[k], b[k], s);
    return s;
}
// async global->LDS DMA, 16B/lane; LDS base wave-uniform (HW adds lane*16)
__device__ __forceinline__ void gload_lds16(const void* g, void* l) {
    __builtin_amdgcn_global_load_lds(
        (const __attribute__((address_space(1))) unsigned int*)g,
        (__attribute__((address_space(3))) unsigned int*)l,
        16, 0, 0);
}

// ---------------------------------------------------------------------------
// qprep: build the Q image FRAGMENT-ORDERED (48 KB): 16B block
// idx = s*256 + w*64 + lane  holds the A-fragment lane `lane` of wave `w`
// needs at k-step s:  Q[w*32 + (lane&31)][ (lane>>5)*8 + s*16 .. +7 ] (bf16).
// The per-block hoist then reads 12 x 1KB fully-coalesced wave-loads
// (16 lines each) instead of r17's 32-line row-gather per instruction.
// ---------------------------------------------------------------------------
__global__ __launch_bounds__(256) void qprep(
    const float* __restrict__ Qf, unsigned short* __restrict__ Qi)
{
    const int b = blockIdx.x * 256 + threadIdx.x;    // 3072 16B blocks
    if (b >= 12 * 256) return;
    const int s = b >> 8, w = (b >> 6) & 3, lane = b & 63;
    const int q  = w * 32 + (lane & 31);
    const int k0 = (lane >> 5) * 8 + s * 16;
    const float* qp = Qf + q * DK + k0;
    unsigned short* dst = Qi + (size_t)b * 8;
    #pragma unroll
    for (int e = 0; e < 8; ++e) dst[e] = (unsigned short)f2bf_rne(qp[e]);
}

// ---------------------------------------------------------------------------
// Straight-line MFMA scoring block: ONE 64-item chunk x all 128 queries.
// G arrives via global_load_lds DMA (12 instrs, pre-swizzled source).
// Q fragments hoisted from the FRAGMENT-ORDERED image (12 coalesced 1KB
// wave-loads, L2-hot) into 48 VGPRs, PINNED so they can't be sunk into the
// loop. This removes r16/r17's 32-line-per-instruction Q gather - the
// measured ~20us/block serial latency (warm-replay == cold-replay proved
// the pass was TA/latency-bound, not BW-bound).
// D = mfma(A=Q, B=G): 2 item-tiles, 12 x {4 ds_read + 8 v_perm + 2 MFMA}.
// LDS ~51 KB -> 3 blocks/CU.
// MODE 0: masked per-(chunk,q) bf16 max -> gmax[blockIdx][q]   (sampled)
// MODE 1: threshold filter -> LDS queue -> exact fp32 wave-rescore ->
//         dense per-q list via 64B-padded global counters
// ---------------------------------------------------------------------------
template<int MODE>
__global__ __launch_bounds__(256, 2) void score_pass(
    const float* __restrict__ Qf, const unsigned short* __restrict__ Qi,
    const float* __restrict__ G,
    const int* __restrict__ mask, const float* __restrict__ thrm,
    float* __restrict__ gmax,
    int* __restrict__ gcnt, float* __restrict__ cs, int* __restrict__ ci,
    int* __restrict__ ocnt, int* __restrict__ oq, int* __restrict__ og,
    float* __restrict__ osv,
    int Ntot, int NCH, int SC)
{
    __shared__ float    Gf[CHI * DK];      // 48 KB fp32 G tile (swizzled img)
    __shared__ float    thrmS[BQ];
    __shared__ unsigned queue[QCAP];
    __shared__ int      qn;

    const int t = threadIdx.x;
    const int w = t >> 6, lane = t & 63;
    const int lo5 = lane & 31, hi = lane >> 5;
    const int qbW = w * 32;

    const int chunk = (MODE == 0)
        ? (int)(((long long)blockIdx.x * NCH) / SC)
        : (int)blockIdx.x;
    const int cb = chunk * CHI;

    // ---- G DMA first: 12 instrs, pre-swizzled source (r14/r16/r17 math)
    #pragma unroll
    for (int i = 0; i < 12; ++i) {
        const int slot = t + (i << 8);
        const int r = slot / 48, c = slot - r * 48;
        size_t grow = (size_t)cb + r;
        if (grow >= (size_t)Ntot) grow = (size_t)Ntot - 1;   // safe dup
        const char* gp = (const char*)G + grow * (DK * 4) + ((c ^ (r & 7)) << 4);
        char* lp = (char*)Gf + ((i << 2) + w) * 1024;        // wave-uniform
        gload_lds16(gp, lp);
    }

    // ---- hoist Q fragments: 12 coalesced 1KB wave-loads (L2-hot), PINNED
    uint4 aF[12];
    {
        const uint4* qp = reinterpret_cast<const uint4*>(Qi) + (w << 6) + lane;
        #pragma unroll
        for (int s = 0; s < 12; ++s)
            aF[s] = qp[s << 8];                  // idx = s*256 + w*64 + lane
    }
    #pragma unroll
    for (int s = 0; s < 12; ++s)
        asm volatile("" : "+v"(aF[s].x), "+v"(aF[s].y),
                          "+v"(aF[s].z), "+v"(aF[s].w));   // forbid sinking

    if (t < BQ) thrmS[t] = (MODE == 1) ? thrm[t] : 0.f;
    if (t == 0) qn = 0;
    __syncthreads();                 // drains DMA (vmcnt before s_barrier)

    const unsigned xsh = (unsigned)((lo5 & 7) << 4);
    const char* rowp0 = (const char*)Gf + lo5 * (DK * 4);          // tile 0
    const char* rowp1 = (const char*)Gf + (32 + lo5) * (DK * 4);   // tile 1

    f32x16 acc[2] = {
        {0,0,0,0,0,0,0,0,0,0,0,0,0,0,0,0}, {0,0,0,0,0,0,0,0,0,0,0,0,0,0,0,0}};
    #pragma unroll
    for (int s = 0; s < 12; ++s) {
        const unsigned b0 = ((unsigned)((s * 4 + hi * 2) << 4)) ^ xsh;
        const unsigned b1 = ((unsigned)((s * 4 + hi * 2 + 1) << 4)) ^ xsh;
        union { uint4 u; short8v v; } au; au.u = aF[s];
        {
            float4 f0 = *reinterpret_cast<const float4*>(rowp0 + b0);
            float4 f1 = *reinterpret_cast<const float4*>(rowp0 + b1);
            union { unsigned u[4]; short8v v; } bu;
            bu.u[0] = pk_trunc(f0.x, f0.y); bu.u[1] = pk_trunc(f0.z, f0.w);
            bu.u[2] = pk_trunc(f1.x, f1.y); bu.u[3] = pk_trunc(f1.z, f1.w);
            acc[0] = __builtin_amdgcn_mfma_f32_32x32x16_bf16(au.v, bu.v, acc[0], 0, 0, 0);
        }
        {
            float4 f0 = *reinterpret_cast<const float4*>(rowp1 + b0);
            float4 f1 = *reinterpret_cast<const float4*>(rowp1 + b1);
            union { unsigned u[4]; short8v v; } bu;
            bu.u[0] = pk_trunc(f0.x, f0.y); bu.u[1] = pk_trunc(f0.z, f0.w);
            bu.u[2] = pk_trunc(f1.x, f1.y); bu.u[3] = pk_trunc(f1.z, f1.w);
            acc[1] = __builtin_amdgcn_mfma_f32_32x32x16_bf16(au.v, bu.v, acc[1], 0, 0, 0);
        }
    }

    // D layout: row(query) = (j&3)+8*(j>>2)+4*hi (+qbW), col(item) = lane&31
    if (MODE == 0) {
        #pragma unroll
        for (int j = 0; j < 16; ++j) {
            const int row = (j & 3) + 8 * (j >> 2) + 4 * hi;
            const int q = qbW + row;
            const size_t mrow = (size_t)q * (size_t)Ntot;
            float m = NEG_INF;
            #pragma unroll
            for (int st = 0; st < 2; ++st) {
                const int g = cb + st * 32 + lo5;
                if (g < Ntot && !mask[mrow + g]) m = fmaxf(m, acc[st][j]);
            }
            #pragma unroll
            for (int off = 1; off < 32; off <<= 1)        // within 32-lane half
                m = fmaxf(m, __shfl_xor(m, off));
            if (lo5 == 0) gmax[(size_t)blockIdx.x * BQ + q] = m;
        }
    } else {
        #pragma unroll
        for (int j = 0; j < 16; ++j) {
            const int row = (j & 3) + 8 * (j >> 2) + 4 * hi;
            const int q = qbW + row;
            const float th = thrmS[q];
            #pragma unroll
            for (int st = 0; st < 2; ++st) {
                const int g = cb + st * 32 + lo5;
                const float s = acc[st][j];
                if (g < Ntot && s >= th) {
                    if (!mask[(size_t)q * (size_t)Ntot + g]) {   // coalesced
                        const int p = atomicAdd(&qn, 1);
                        if (p < QCAP) {
                            queue[p] = ((unsigned)q << 24) | (unsigned)g;
                        } else {   // pathological: inline exact rescore
                            float sx = dot192(Qf + q * DK, G + (size_t)g * DK);
                            const int op = atomicAdd(ocnt, 1);
                            if (op < OCAP) { oq[op] = q; og[op] = g; osv[op] = sx; }
                        }
                    }
                }
            }
        }
        __syncthreads();
        const int nq = qn < QCAP ? qn : QCAP;
        for (int cc = w; cc < nq; cc += 4) {       // one wave per candidate
            const unsigned pk = queue[cc];
            const int q = pk >> 24, gg = pk & 0xFFFFFF;
            const float* qr = Qf + q * DK;
            const float* gr = G + (size_t)gg * DK;
            const int k0 = lane * 3;
            float part = qr[k0] * gr[k0];
            part = fmaf(qr[k0 + 1], gr[k0 + 1], part);
            part = fmaf(qr[k0 + 2], gr[k0 + 2], part);
            #pragma unroll
            for (int off = 32; off > 0; off >>= 1)
                part += __shfl_xor(part, off);
            if (lane == 0) {
                const int pos = atomicAdd(&gcnt[q * 16], 1);   // 64B-padded
                if (pos < CAP) {
                    cs[(size_t)q * CAP + pos] = part;
                    ci[(size_t)q * CAP + pos] = gg;
                } else {
                    const int op = atomicAdd(ocnt, 1);
                    if (op < OCAP) { oq[op] = q; og[op] = gg; osv[op] = part; }
                }
            }
        }
    }
}

// ---------------------------------------------------------------------------
// thrm[q] = (exact 32nd-largest of SC sampled masked chunk-maxima) - MARGIN.
// Valid bound: 32 distinct unmasked witnesses with bf16 score >= thr.
// ---------------------------------------------------------------------------
__global__ __launch_bounds__(256) void thr32(
    const float* __restrict__ gmax, float* __restrict__ thrm, int SC)
{
    __shared__ float vals[THRV];
    __shared__ int hist[256];
    __shared__ int hscan[256];
    __shared__ int bS, gtS;

    const int q = blockIdx.x;
    const int t = threadIdx.x;
    const int M = SC < THRV ? SC : THRV;

    for (int i = t; i < M; i += 256) {
        float m = gmax[(size_t)i * BQ + q];
        for (int j = i + THRV; j < SC; j += THRV)
            m = fmaxf(m, gmax[(size_t)j * BQ + q]);
        vals[i] = m;
    }
    __syncthreads();

    unsigned prefix = 0, pmask = 0;
    int kneed = KTOP;
    for (int pass = 0; pass < 4; ++pass) {
        const int shift = 24 - pass * 8;
        hist[t] = 0;
        __syncthreads();
        for (int i = t; i < M; i += 256) {
            unsigned k = fkey(vals[i]);
            if ((k & pmask) == prefix) atomicAdd(&hist[(k >> shift) & 255], 1);
        }
        __syncthreads();
        int* src = hist; int* dst = hscan;
        for (int off = 1; off < 256; off <<= 1) {
            int v = src[t] + ((t + off) < 256 ? src[t + off] : 0);
            __syncthreads();
            dst[t] = v;
            __syncthreads();
            int* tmp = src; src = dst; dst = tmp;
        }
        if (src[t] >= kneed && (t == 255 || src[t + 1] < kneed)) {
            bS = t; gtS = (t == 255) ? 0 : src[t + 1];
        }
        __syncthreads();
        kneed -= gtS;
        prefix |= ((unsigned)bS) << shift;
        pmask  |= 0xFFu << shift;
        __syncthreads();
    }
    if (t == 0) {
        unsigned u = (prefix & 0x80000000u) ? (prefix & 0x7FFFFFFFu) : ~prefix;
        thrm[q] = __uint_as_float(u) - MARGIN;
    }
}

// ---------------------------------------------------------------------------
// Exact per-query top-32 over dense candidate list (+overflow): 4-pass radix
// select + collect + tie-breaking tournament (score desc, idx asc).
// out: [0..B*K) = indices (as float); [B*K..2BK) = scores.
// ---------------------------------------------------------------------------
__global__ __launch_bounds__(256) void select_topk(
    const float* __restrict__ cs, const int* __restrict__ ci,
    const int* __restrict__ gcnt,
    const int* __restrict__ ocnt, const int* __restrict__ oq,
    const int* __restrict__ og, const float* __restrict__ osv,
    float* __restrict__ out)
{
    __shared__ int   hist[256];
    __shared__ int   hscan[256];
    __shared__ float Ls[256];
    __shared__ int   Li[256];
    __shared__ int   lcnt, nTotS, bS, gtS;
    __shared__ float wrs[4]; __shared__ int wri[4], wrslot[4];

    const int q = blockIdx.x;
    const int t = threadIdx.x;
    const int n0 = gcnt[q * 16];
    const int n = n0 < CAP ? n0 : CAP;
    const size_t base = (size_t)q * CAP;
    const int novf0 = *ocnt;
    const int novf = novf0 < OCAP ? novf0 : OCAP;

    if (t == 0) nTotS = 0;
    __syncthreads();
    {
        int part = (t == 0) ? n : 0;
        for (int i = t; i < novf; i += 256)
            if (oq[i] == q) part++;
        atomicAdd(&nTotS, part);
    }
    __syncthreads();
    const int nTot = nTotS;

    unsigned prefix = 0, pmask = 0;
    int kneed = KTOP;

    if (nTot > KTOP) {
        for (int pass = 0; pass < 4; ++pass) {
            const int shift = 24 - pass * 8;
            hist[t] = 0;
            __syncthreads();
            for (int i = t; i < n; i += 256) {
                unsigned k = fkey(cs[base + i]);
                if ((k & pmask) == prefix)
                    atomicAdd(&hist[(k >> shift) & 255], 1);
            }
            for (int i = t; i < novf; i += 256) {
                if (oq[i] == q) {
                    unsigned k = fkey(osv[i]);
                    if ((k & pmask) == prefix)
                        atomicAdd(&hist[(k >> shift) & 255], 1);
                }
            }
            __syncthreads();
            int* src = hist; int* dst = hscan;
            for (int off = 1; off < 256; off <<= 1) {
                int v = src[t] + ((t + off) < 256 ? src[t + off] : 0);
                __syncthreads();
                dst[t] = v;
                __syncthreads();
                int* tmp = src; src = dst; dst = tmp;
            }
            if (src[t] >= kneed && (t == 255 || src[t + 1] < kneed)) {
                bS = t;
                gtS = (t == 255) ? 0 : src[t + 1];
            }
            __syncthreads();
            const int b = bS;
            kneed -= gtS;
            prefix |= ((unsigned)b) << shift;
            pmask  |= 0xFFu << shift;
            __syncthreads();
        }
    }

    if (t == 0) lcnt = 0;
    __syncthreads();
    const unsigned T = (nTot > KTOP) ? prefix : 0u;
    for (int i = t; i < n; i += 256) {
        float s = cs[base + i];
        if (fkey(s) >= T) {
            int p = atomicAdd(&lcnt, 1);
            if (p < 256) { Ls[p] = s; Li[p] = ci[base + i]; }
        }
    }
    for (int i = t; i < novf; i += 256) {
        if (oq[i] == q) {
            float s = osv[i];
            if (fkey(s) >= T) {
                int p = atomicAdd(&lcnt, 1);
                if (p < 256) { Ls[p] = s; Li[p] = og[i]; }
            }
        }
    }
    __syncthreads();
    const int M = lcnt < 256 ? lcnt : 256;

    const int w = t >> 6, lane = t & 63;
    for (int r = 0; r < KTOP; ++r) {
        float bv = (t < M) ? Ls[t] : NEG_INF;
        int   bi = (t < M) ? Li[t] : 0x7fffffff;
        int   bslot = t;
        #pragma unroll
        for (int off = 32; off > 0; off >>= 1) {
            float ov = __shfl_xor(bv, off);
            int   oi = __shfl_xor(bi, off);
            int   osl = __shfl_xor(bslot, off);
            if (pri_gt(ov, oi, bv, bi)) { bv = ov; bi = oi; bslot = osl; }
        }
        if (lane == 0) { wrs[w] = bv; wri[w] = bi; wrslot[w] = bslot; }
        __syncthreads();
        if (t == 0) {
            float fv = wrs[0]; int fi = wri[0]; int fs = wrslot[0];
            #pragma unroll
            for (int ww = 1; ww < 4; ++ww)
                if (pri_gt(wrs[ww], wri[ww], fv, fi)) {
                    fv = wrs[ww]; fi = wri[ww]; fs = wrslot[ww];
                }
            out[q * KTOP + r]                     = (float)fi;
            out[(size_t)BQ * KTOP + q * KTOP + r] = fv;
            Ls[fs] = NEG_INF; Li[fs] = 0x7fffffff;
        }
        __syncthreads();
    }
}

// ---------------------------------------------------------------------------
extern "C" void kernel_launch(void* const* d_in, const int* in_sizes, int n_in,
                              void* d_out, int out_size, void* d_ws, size_t ws_size,
                              hipStream_t stream)
{
    const float* Qf   = (const float*)d_in[0];
    const float* G    = (const float*)d_in[1];
    const int*   mask = (const int*)d_in[2];
    const int Ntot = in_sizes[1] / DK;                 // 200000

    const int NCH = (Ntot + CHI - 1) / CHI;            // 3125
    int SC = SCN;                                      // 768 sampled chunks
    if (SC > NCH) SC = NCH;

    // ws layout (bytes): ~9.5 MB total
    char* w = (char*)d_ws;
    int*   ocnt = (int*)(w + 0);                       // [0, 1024) control
    int*   gcnt = (int*)(w + 1024);                    // 128 ctrs, 64B apart
    float* thrm = (float*)(w + 10240);                 // 512 B
    unsigned short* Qi = (unsigned short*)(w + 16384); // 48 KB fragment image
    size_t off = 16384 + (size_t)BQ * DK * 2;
    off = (off + 255) & ~(size_t)255;
    float* gmax = (float*)(w + off);                   // SC*128*4
    off += (size_t)SC * BQ * 4; off = (off + 255) & ~(size_t)255;
    float* cs   = (float*)(w + off);                   // 128*CAP*4 = 4 MB
    off += (size_t)BQ * CAP * 4;
    int*   ci   = (int*)(w + off);                     // 4 MB
    off += (size_t)BQ * CAP * 4;
    int*   oqv  = (int*)(w + off);   off += (size_t)OCAP * 4;
    int*   ogv  = (int*)(w + off);   off += (size_t)OCAP * 4;
    float* osv  = (float*)(w + off);

    (void)hipMemsetAsync(w, 0, 16384, stream);
    qprep<<<dim3((12 * 256 + 255) / 256), dim3(256), 0, stream>>>(Qf, Qi);
    score_pass<0><<<dim3(SC), dim3(256), 0, stream>>>(      // sampled maxima
        Qf, Qi, G, mask, thrm, gmax, gcnt, cs, ci, ocnt, oqv, ogv, osv,
        Ntot, NCH, SC);
    thr32<<<dim3(BQ), dim3(256), 0, stream>>>(gmax, thrm, SC);
    score_pass<1><<<dim3(NCH), dim3(256), 0, stream>>>(     // full filter
        Qf, Qi, G, mask, thrm, gmax, gcnt, cs, ci, ocnt, oqv, ogv, osv,
        Ntot, NCH, SC);
    select_topk<<<dim3(BQ), dim3(256), 0, stream>>>(
        cs, ci, gcnt, ocnt, oqv, ogv, osv, (float*)d_out);
}

// Round 19
// 123.746 us; speedup vs baseline: 2.3514x; 1.0546x over previous
//
#include <hip/hip_runtime.h>
#include <hip/hip_bf16.h>
#include <cstdint>
#include <cstddef>

#define BQ 128        // queries (problem-fixed)
#define DK 192        // SIG_DIM
#define KTOP 32
#define CHI 32        // gallery items per chunk (one MFMA tile per block)
#define QCAP 512      // per-block LDS rescore queue
#define CAP 8192      // dense candidate list capacity per query
#define OCAP 65536    // global overflow list
#define MARGIN 0.02f  // > 2x (trunc-G + rne-Q) dot error bound (~0.012)
#define SCN 768       // sampled chunks for threshold
#define THRV 3200     // thr32 LDS value slots

#define NEG_INF (-__builtin_huge_valf())

typedef short short8v __attribute__((ext_vector_type(8)));
typedef float f32x16  __attribute__((ext_vector_type(16)));

__device__ __forceinline__ unsigned fkey(float s) {
    unsigned u = __float_as_uint(s);
    return (u & 0x80000000u) ? ~u : (u | 0x80000000u);   // monotone f32 -> u32
}
__device__ __forceinline__ bool pri_gt(float s1, int i1, float s2, int i2) {
    return (s1 > s2) || (s1 == s2 && i1 < i2);           // jax top_k stability
}
// pack {bf16_trunc(b) : bf16_trunc(a)} in one v_perm_b32 (high halves)
__device__ __forceinline__ unsigned pk_trunc(float a, float b) {
    return __builtin_amdgcn_perm(__float_as_uint(b), __float_as_uint(a),
                                 0x07060302u);
}
__device__ __forceinline__ unsigned f2bf_rne(float x) {
    unsigned u = __float_as_uint(x);
    unsigned r = u + 0x7FFFu + ((u >> 16) & 1u);
    return r >> 16;
}
__device__ __forceinline__ float dot192(const float* __restrict__ a,
                                        const float* __restrict__ b) {
    float s = 0.f;
    #pragma unroll 8
    for (int k = 0; k < DK; ++k) s = fmaf(a[k], b[k], s);
    return s;
}

// ---------------------------------------------------------------------------
// qprep: Q image FRAGMENT-ORDERED (48 KB): 16B block idx = s*256 + w*64 + lane
// holds A-fragment for wave w, lane, k-step s (r18-verified).
// ---------------------------------------------------------------------------
__global__ __launch_bounds__(256) void qprep(
    const float* __restrict__ Qf, unsigned short* __restrict__ Qi)
{
    const int b = blockIdx.x * 256 + threadIdx.x;    // 3072 16B blocks
    if (b >= 12 * 256) return;
    const int s = b >> 8, w = (b >> 6) & 3, lane = b & 63;
    const int q  = w * 32 + (lane & 31);
    const int k0 = (lane >> 5) * 8 + s * 16;
    const float* qp = Qf + q * DK + k0;
    unsigned short* dst = Qi + (size_t)b * 8;
    #pragma unroll
    for (int e = 0; e < 8; ++e) dst[e] = (unsigned short)f2bf_rne(qp[e]);
}

// ---------------------------------------------------------------------------
// Straight-line MFMA scoring block: ONE 32-item chunk x all 128 queries.
// G staged via REGULAR float4 loads -> registers -> pk_trunc -> swizzled
// ds_write_b64 (HipKittens reg-staging pattern). Replaces global_load_lds:
// every DMA variant (r13-r18) pinned at ~1 TB/s effective with warm==cold
// replay time, i.e. the DMA path itself was the ~20us/block constant.
// Regular loads measured 6.3 TB/s (m13). Tile stored bf16 (12 KB): halves
// LDS traffic, removes all in-loop v_perm, LDS ~15 KB -> ~4 blocks/CU.
// Q fragments: 12 coalesced wave-loads from fragment image, PINNED (r18).
// MODE 0: masked per-(chunk,q) bf16 max -> gmax[blockIdx][q]   (sampled)
// MODE 1: threshold filter -> LDS queue -> exact fp32 wave-rescore ->
//         dense per-q list via 64B-padded global counters
// ---------------------------------------------------------------------------
template<int MODE>
__global__ __launch_bounds__(256, 2) void score_pass(
    const float* __restrict__ Qf, const unsigned short* __restrict__ Qi,
    const float* __restrict__ G,
    const int* __restrict__ mask, const float* __restrict__ thrm,
    float* __restrict__ gmax,
    int* __restrict__ gcnt, float* __restrict__ cs, int* __restrict__ ci,
    int* __restrict__ ocnt, int* __restrict__ oq, int* __restrict__ og,
    float* __restrict__ osv,
    int Ntot, int NCH, int SC)
{
    __shared__ unsigned char Gb[CHI * 384];   // 12 KB bf16 G tile (swizzled)
    __shared__ float    thrmS[BQ];
    __shared__ unsigned queue[QCAP];
    __shared__ int      qn;

    const int t = threadIdx.x;
    const int w = t >> 6, lane = t & 63;
    const int lo5 = lane & 31, hi = lane >> 5;
    const int qbW = w * 32;

    const int chunk = (MODE == 0)
        ? (int)(((long long)blockIdx.x * NCH) / SC)
        : (int)blockIdx.x;
    const int cb = chunk * CHI;

    // ---- G loads FIRST (HBM long pole): 6 coalesced float4 per thread
    float4 ld[6];
    int srow[6], sc4[6];
    {
        const float4* src = reinterpret_cast<const float4*>(G) + (size_t)cb * 48;
        #pragma unroll
        for (int i = 0; i < 6; ++i) {
            const int slot = t + (i << 8);            // 0..1535
            const int r = slot / 48, c = slot - r * 48;
            srow[i] = r; sc4[i] = c;
            const int gr = (cb + r < Ntot) ? slot : (slot - (cb + r - (Ntot - 1)) * 48);
            ld[i] = src[gr];                          // dup last row if OOB
        }
    }
    // ---- Q fragment hoist (L2-hot, coalesced, in flight with G loads)
    uint4 aF[12];
    {
        const uint4* qp = reinterpret_cast<const uint4*>(Qi) + (w << 6) + lane;
        #pragma unroll
        for (int s = 0; s < 12; ++s)
            aF[s] = qp[s << 8];
    }
    #pragma unroll
    for (int s = 0; s < 12; ++s)
        asm volatile("" : "+v"(aF[s].x), "+v"(aF[s].y),
                          "+v"(aF[s].z), "+v"(aF[s].w));   // forbid sinking

    // ---- stage G: fp32 -> bf16 (pk_trunc), XOR-swizzled ds_write_b64
    #pragma unroll
    for (int i = 0; i < 6; ++i) {
        const int r = srow[i], c = sc4[i];
        const uint2 p = make_uint2(pk_trunc(ld[i].x, ld[i].y),
                                   pk_trunc(ld[i].z, ld[i].w));
        const int blk = (c >> 1) ^ (r & 7);           // bf16 16B-block swizzle
        *reinterpret_cast<uint2*>(Gb + r * 384 + blk * 16 + (c & 1) * 8) = p;
    }

    if (t < BQ) thrmS[t] = (MODE == 1) ? thrm[t] : 0.f;
    if (t == 0) qn = 0;
    __syncthreads();

    // ---- MFMA loop: A = pinned Q regs, B = bf16 ds_read_b128 (swizzled)
    const unsigned xsh = (unsigned)((lo5 & 7) << 4);
    const unsigned char* rowp = Gb + lo5 * 384;

    f32x16 acc = {0,0,0,0,0,0,0,0,0,0,0,0,0,0,0,0};
    #pragma unroll
    for (int s = 0; s < 12; ++s) {
        union { uint4 u; short8v v; } au; au.u = aF[s];
        union { uint4 u; short8v v; } bu;
        bu.u = *reinterpret_cast<const uint4*>(
            rowp + (((unsigned)((s * 2 + hi) << 4)) ^ xsh));
        acc = __builtin_amdgcn_mfma_f32_32x32x16_bf16(au.v, bu.v, acc, 0, 0, 0);
    }

    // D layout: row(query) = (j&3)+8*(j>>2)+4*hi (+qbW), col(item) = lane&31
    const int g = cb + lo5;
    if (MODE == 0) {
        #pragma unroll
        for (int j = 0; j < 16; ++j) {
            const int row = (j & 3) + 8 * (j >> 2) + 4 * hi;
            const int q = qbW + row;
            float m = NEG_INF;
            if (g < Ntot && !mask[(size_t)q * (size_t)Ntot + g])
                m = acc[j];
            #pragma unroll
            for (int off = 1; off < 32; off <<= 1)
                m = fmaxf(m, __shfl_xor(m, off));
            if (lo5 == 0) gmax[(size_t)blockIdx.x * BQ + q] = m;
        }
    } else {
        #pragma unroll
        for (int j = 0; j < 16; ++j) {
            const int row = (j & 3) + 8 * (j >> 2) + 4 * hi;
            const int q = qbW + row;
            const float th = thrmS[q];
            const float s = acc[j];
            if (g < Ntot && s >= th) {
                if (!mask[(size_t)q * (size_t)Ntot + g]) {   // coalesced
                    const int p = atomicAdd(&qn, 1);
                    if (p < QCAP) {
                        queue[p] = ((unsigned)q << 24) | (unsigned)g;
                    } else {   // pathological: inline exact rescore
                        float sx = dot192(Qf + q * DK, G + (size_t)g * DK);
                        const int op = atomicAdd(ocnt, 1);
                        if (op < OCAP) { oq[op] = q; og[op] = g; osv[op] = sx; }
                    }
                }
            }
        }
        __syncthreads();
        const int nq = qn < QCAP ? qn : QCAP;
        for (int cc = w; cc < nq; cc += 4) {       // one wave per candidate
            const unsigned pk = queue[cc];
            const int q = pk >> 24, gg = pk & 0xFFFFFF;
            const float* qr = Qf + q * DK;
            const float* gr = G + (size_t)gg * DK;
            const int k0 = lane * 3;
            float part = qr[k0] * gr[k0];
            part = fmaf(qr[k0 + 1], gr[k0 + 1], part);
            part = fmaf(qr[k0 + 2], gr[k0 + 2], part);
            #pragma unroll
            for (int off = 32; off > 0; off >>= 1)
                part += __shfl_xor(part, off);
            if (lane == 0) {
                const int pos = atomicAdd(&gcnt[q * 16], 1);   // 64B-padded
                if (pos < CAP) {
                    cs[(size_t)q * CAP + pos] = part;
                    ci[(size_t)q * CAP + pos] = gg;
                } else {
                    const int op = atomicAdd(ocnt, 1);
                    if (op < OCAP) { oq[op] = q; og[op] = gg; osv[op] = part; }
                }
            }
        }
    }
}

// ---------------------------------------------------------------------------
// thrm[q] = (exact 32nd-largest of SC sampled masked chunk-maxima) - MARGIN.
// Valid bound: 32 distinct unmasked witnesses with bf16 score >= thr.
// ---------------------------------------------------------------------------
__global__ __launch_bounds__(256) void thr32(
    const float* __restrict__ gmax, float* __restrict__ thrm, int SC)
{
    __shared__ float vals[THRV];
    __shared__ int hist[256];
    __shared__ int hscan[256];
    __shared__ int bS, gtS;

    const int q = blockIdx.x;
    const int t = threadIdx.x;
    const int M = SC < THRV ? SC : THRV;

    for (int i = t; i < M; i += 256) {
        float m = gmax[(size_t)i * BQ + q];
        for (int j = i + THRV; j < SC; j += THRV)
            m = fmaxf(m, gmax[(size_t)j * BQ + q]);
        vals[i] = m;
    }
    __syncthreads();

    unsigned prefix = 0, pmask = 0;
    int kneed = KTOP;
    for (int pass = 0; pass < 4; ++pass) {
        const int shift = 24 - pass * 8;
        hist[t] = 0;
        __syncthreads();
        for (int i = t; i < M; i += 256) {
            unsigned k = fkey(vals[i]);
            if ((k & pmask) == prefix) atomicAdd(&hist[(k >> shift) & 255], 1);
        }
        __syncthreads();
        int* src = hist; int* dst = hscan;
        for (int off = 1; off < 256; off <<= 1) {
            int v = src[t] + ((t + off) < 256 ? src[t + off] : 0);
            __syncthreads();
            dst[t] = v;
            __syncthreads();
            int* tmp = src; src = dst; dst = tmp;
        }
        if (src[t] >= kneed && (t == 255 || src[t + 1] < kneed)) {
            bS = t; gtS = (t == 255) ? 0 : src[t + 1];
        }
        __syncthreads();
        kneed -= gtS;
        prefix |= ((unsigned)bS) << shift;
        pmask  |= 0xFFu << shift;
        __syncthreads();
    }
    if (t == 0) {
        unsigned u = (prefix & 0x80000000u) ? (prefix & 0x7FFFFFFFu) : ~prefix;
        thrm[q] = __uint_as_float(u) - MARGIN;
    }
}

// ---------------------------------------------------------------------------
// Exact per-query top-32 over dense candidate list (+overflow): 4-pass radix
// select + collect + tie-breaking tournament (score desc, idx asc).
// out: [0..B*K) = indices (as float); [B*K..2BK) = scores.
// ---------------------------------------------------------------------------
__global__ __launch_bounds__(256) void select_topk(
    const float* __restrict__ cs, const int* __restrict__ ci,
    const int* __restrict__ gcnt,
    const int* __restrict__ ocnt, const int* __restrict__ oq,
    const int* __restrict__ og, const float* __restrict__ osv,
    float* __restrict__ out)
{
    __shared__ int   hist[256];
    __shared__ int   hscan[256];
    __shared__ float Ls[256];
    __shared__ int   Li[256];
    __shared__ int   lcnt, nTotS, bS, gtS;
    __shared__ float wrs[4]; __shared__ int wri[4], wrslot[4];

    const int q = blockIdx.x;
    const int t = threadIdx.x;
    const int n0 = gcnt[q * 16];
    const int n = n0 < CAP ? n0 : CAP;
    const size_t base = (size_t)q * CAP;
    const int novf0 = *ocnt;
    const int novf = novf0 < OCAP ? novf0 : OCAP;

    if (t == 0) nTotS = 0;
    __syncthreads();
    {
        int part = (t == 0) ? n : 0;
        for (int i = t; i < novf; i += 256)
            if (oq[i] == q) part++;
        atomicAdd(&nTotS, part);
    }
    __syncthreads();
    const int nTot = nTotS;

    unsigned prefix = 0, pmask = 0;
    int kneed = KTOP;

    if (nTot > KTOP) {
        for (int pass = 0; pass < 4; ++pass) {
            const int shift = 24 - pass * 8;
            hist[t] = 0;
            __syncthreads();
            for (int i = t; i < n; i += 256) {
                unsigned k = fkey(cs[base + i]);
                if ((k & pmask) == prefix)
                    atomicAdd(&hist[(k >> shift) & 255], 1);
            }
            for (int i = t; i < novf; i += 256) {
                if (oq[i] == q) {
                    unsigned k = fkey(osv[i]);
                    if ((k & pmask) == prefix)
                        atomicAdd(&hist[(k >> shift) & 255], 1);
                }
            }
            __syncthreads();
            int* src = hist; int* dst = hscan;
            for (int off = 1; off < 256; off <<= 1) {
                int v = src[t] + ((t + off) < 256 ? src[t + off] : 0);
                __syncthreads();
                dst[t] = v;
                __syncthreads();
                int* tmp = src; src = dst; dst = tmp;
            }
            if (src[t] >= kneed && (t == 255 || src[t + 1] < kneed)) {
                bS = t;
                gtS = (t == 255) ? 0 : src[t + 1];
            }
            __syncthreads();
            const int b = bS;
            kneed -= gtS;
            prefix |= ((unsigned)b) << shift;
            pmask  |= 0xFFu << shift;
            __syncthreads();
        }
    }

    if (t == 0) lcnt = 0;
    __syncthreads();
    const unsigned T = (nTot > KTOP) ? prefix : 0u;
    for (int i = t; i < n; i += 256) {
        float s = cs[base + i];
        if (fkey(s) >= T) {
            int p = atomicAdd(&lcnt, 1);
            if (p < 256) { Ls[p] = s; Li[p] = ci[base + i]; }
        }
    }
    for (int i = t; i < novf; i += 256) {
        if (oq[i] == q) {
            float s = osv[i];
            if (fkey(s) >= T) {
                int p = atomicAdd(&lcnt, 1);
                if (p < 256) { Ls[p] = s; Li[p] = og[i]; }
            }
        }
    }
    __syncthreads();
    const int M = lcnt < 256 ? lcnt : 256;

    const int w = t >> 6, lane = t & 63;
    for (int r = 0; r < KTOP; ++r) {
        float bv = (t < M) ? Ls[t] : NEG_INF;
        int   bi = (t < M) ? Li[t] : 0x7fffffff;
        int   bslot = t;
        #pragma unroll
        for (int off = 32; off > 0; off >>= 1) {
            float ov = __shfl_xor(bv, off);
            int   oi = __shfl_xor(bi, off);
            int   osl = __shfl_xor(bslot, off);
            if (pri_gt(ov, oi, bv, bi)) { bv = ov; bi = oi; bslot = osl; }
        }
        if (lane == 0) { wrs[w] = bv; wri[w] = bi; wrslot[w] = bslot; }
        __syncthreads();
        if (t == 0) {
            float fv = wrs[0]; int fi = wri[0]; int fs = wrslot[0];
            #pragma unroll
            for (int ww = 1; ww < 4; ++ww)
                if (pri_gt(wrs[ww], wri[ww], fv, fi)) {
                    fv = wrs[ww]; fi = wri[ww]; fs = wrslot[ww];
                }
            out[q * KTOP + r]                     = (float)fi;
            out[(size_t)BQ * KTOP + q * KTOP + r] = fv;
            Ls[fs] = NEG_INF; Li[fs] = 0x7fffffff;
        }
        __syncthreads();
    }
}

// ---------------------------------------------------------------------------
extern "C" void kernel_launch(void* const* d_in, const int* in_sizes, int n_in,
                              void* d_out, int out_size, void* d_ws, size_t ws_size,
                              hipStream_t stream)
{
    const float* Qf   = (const float*)d_in[0];
    const float* G    = (const float*)d_in[1];
    const int*   mask = (const int*)d_in[2];
    const int Ntot = in_sizes[1] / DK;                 // 200000

    const int NCH = (Ntot + CHI - 1) / CHI;            // 6250
    int SC = SCN;                                      // 768 sampled chunks
    if (SC > NCH) SC = NCH;

    // ws layout (bytes): ~9.5 MB total
    char* w = (char*)d_ws;
    int*   ocnt = (int*)(w + 0);                       // [0, 1024) control
    int*   gcnt = (int*)(w + 1024);                    // 128 ctrs, 64B apart
    float* thrm = (float*)(w + 10240);                 // 512 B
    unsigned short* Qi = (unsigned short*)(w + 16384); // 48 KB fragment image
    size_t off = 16384 + (size_t)BQ * DK * 2;
    off = (off + 255) & ~(size_t)255;
    float* gmax = (float*)(w + off);                   // SC*128*4
    off += (size_t)SC * BQ * 4; off = (off + 255) & ~(size_t)255;
    float* cs   = (float*)(w + off);                   // 128*CAP*4 = 4 MB
    off += (size_t)BQ * CAP * 4;
    int*   ci   = (int*)(w + off);                     // 4 MB
    off += (size_t)BQ * CAP * 4;
    int*   oqv  = (int*)(w + off);   off += (size_t)OCAP * 4;
    int*   ogv  = (int*)(w + off);   off += (size_t)OCAP * 4;
    float* osv  = (float*)(w + off);

    (void)hipMemsetAsync(w, 0, 16384, stream);
    qprep<<<dim3((12 * 256 + 255) / 256), dim3(256), 0, stream>>>(Qf, Qi);
    score_pass<0><<<dim3(SC), dim3(256), 0, stream>>>(      // sampled maxima
        Qf, Qi, G, mask, thrm, gmax, gcnt, cs, ci, ocnt, oqv, ogv, osv,
        Ntot, NCH, SC);
    thr32<<<dim3(BQ), dim3(256), 0, stream>>>(gmax, thrm, SC);
    score_pass<1><<<dim3(NCH), dim3(256), 0, stream>>>(     // full filter
        Qf, Qi, G, mask, thrm, gmax, gcnt, cs, ci, ocnt, oqv, ogv, osv,
        Ntot, NCH, SC);
    select_topk<<<dim3(BQ), dim3(256), 0, stream>>>(
        cs, ci, gcnt, ocnt, oqv, ogv, osv, (float*)d_out);
}